// Round 9
// baseline (695.475 us; speedup 1.0000x reference)
//
#include <hip/hip_runtime.h>
#include <cstdint>

#define NN 100000
#define NE 1600000
#define FI 602
#define DD 32
#define CC 41
#define BN_EPS 1e-5f
#define KSTEPS 19                 // 19*32 = 608 >= 602 (k-padded with zeros)

// bucketed CSR build
#define NPB 256                   // nodes per bucket (dst >> 8)
#define NB 391                    // ceil(NN/NPB)
#define EPT 13                    // edges per thread in hist/scatter
#define SCB 481                   // ceil(NE / (256*EPT))

typedef __attribute__((ext_vector_type(8))) short bf16x8;
typedef __attribute__((ext_vector_type(4))) float f32x4;

__device__ __forceinline__ void atomAdd(float* p, float v) {
#ifdef __HIP_PLATFORM_AMD__
  unsafeAtomicAdd(p, v);
#else
  atomicAdd(p, v);
#endif
}

// ---------------- K0: M = lin1_w @ nn1_w1 as MFMA B-fragments (bf16 hi/lo) ; cvec ; zero stats
__global__ __launch_bounds__(256) void k0_prep(
    const float* __restrict__ lin1_w, const float* __restrict__ lin1_b,
    const float* __restrict__ nn1_w1,
    unsigned short* __restrict__ Bhi, unsigned short* __restrict__ Blo,
    float* __restrict__ cvec,
    float* __restrict__ stats1, float* __restrict__ stats2) {
  int o = blockIdx.x * 256 + threadIdx.x;   // over 608*32
  if (o < KSTEPS * 32 * 32) {
    int k = o >> 5, j = o & 31;
    float s = 0.f;
    if (k < FI) {
      #pragma unroll 4
      for (int c = 0; c < 2 * DD; ++c) s = fmaf(lin1_w[k * (2 * DD) + c], nn1_w1[c * DD + j], s);
    }
    int st = k >> 5, kk = k & 31, g = kk >> 3, jj = kk & 7;
    int h = j >> 4, lane = g * 16 + (j & 15);
    int idx = ((st * 2 + h) * 64 + lane) * 8 + jj;
    unsigned ub = __float_as_uint(s);
    unsigned short hi = (unsigned short)(ub >> 16);
    float hv = __uint_as_float((unsigned)hi << 16);
    float d = s - hv;
    Bhi[idx] = hi;
    Blo[idx] = (unsigned short)(__float_as_uint(d) >> 16);
  }
  if (blockIdx.x == 0) {
    int t = threadIdx.x;
    if (t < DD) {
      float s = 0.f;
      for (int c = 0; c < 2 * DD; ++c) s = fmaf(lin1_b[c], nn1_w1[c * DD + t], s);
      cvec[t] = s;
    }
    if (t >= 128 && t < 192) stats1[t - 128] = 0.f;
    if (t >= 192) stats2[t - 192] = 0.f;
  }
}

// ---------------- bucketed CSR build ----------------
__global__ __launch_bounds__(256) void kb_hist(const int* __restrict__ ei, int* __restrict__ bcount) {
  __shared__ int h[NB];
  const int t = threadIdx.x;
  for (int i = t; i < NB; i += 256) h[i] = 0;
  __syncthreads();
  const int base = blockIdx.x * (256 * EPT);
  #pragma unroll
  for (int i = 0; i < EPT; ++i) {
    int e = base + i * 256 + t;
    if (e < NE) atomicAdd(&h[ei[NE + e] >> 8], 1);
  }
  __syncthreads();
  for (int i = t; i < NB; i += 256) if (h[i]) atomicAdd(&bcount[i], h[i]);
}

__global__ __launch_bounds__(512) void kb_scan(const int* __restrict__ bcount,
                                               int* __restrict__ bbase,
                                               int* __restrict__ bcursor,
                                               int* __restrict__ rowstart) {
  __shared__ int ps[512];
  const int t = threadIdx.x;
  int v = (t < NB) ? bcount[t] : 0;
  ps[t] = v;
  __syncthreads();
  #pragma unroll
  for (int off = 1; off < 512; off <<= 1) {
    int u = (t >= off) ? ps[t - off] : 0;
    __syncthreads();
    ps[t] += u;
    __syncthreads();
  }
  int excl = ps[t] - v;
  if (t < NB) { bbase[t] = excl; bcursor[t] = excl; }
  if (t == 0) { bbase[NB] = NE; rowstart[NN] = NE; }
}

__global__ __launch_bounds__(256) void kb_scatter(const int* __restrict__ ei,
                                                  int* __restrict__ bcursor,
                                                  int* __restrict__ tsrc,
                                                  unsigned char* __restrict__ tdst) {
  __shared__ int cnt[NB];
  __shared__ int wbase[NB];
  const int t = threadIdx.x;
  for (int i = t; i < NB; i += 256) cnt[i] = 0;
  __syncthreads();
  const int base = blockIdx.x * (256 * EPT);
  int s[EPT], d[EPT];
  #pragma unroll
  for (int i = 0; i < EPT; ++i) {
    int e = base + i * 256 + t;
    if (e < NE) {
      s[i] = ei[e];
      d[i] = ei[NE + e];
      atomicAdd(&cnt[d[i] >> 8], 1);
    } else {
      s[i] = -1; d[i] = -1;
    }
  }
  __syncthreads();
  for (int i = t; i < NB; i += 256) wbase[i] = atomicAdd(&bcursor[i], cnt[i]);
  __syncthreads();
  #pragma unroll
  for (int i = 0; i < EPT; ++i) {
    if (d[i] >= 0) {
      int p = atomicAdd(&wbase[d[i] >> 8], 1);
      tsrc[p] = s[i];
      tdst[p] = (unsigned char)(d[i] & (NPB - 1));
    }
  }
}

__global__ __launch_bounds__(256) void kb_fine(const int* __restrict__ bbase,
                                               const int* __restrict__ tsrc,
                                               const unsigned char* __restrict__ tdst,
                                               int* __restrict__ rowstart,
                                               int* __restrict__ srcidx) {
  __shared__ int deg[NPB];
  __shared__ int cur[NPB];
  __shared__ int woff[4];
  const int b = blockIdx.x, t = threadIdx.x;
  const int beg = bbase[b], end = bbase[b + 1];
  deg[t] = 0;
  __syncthreads();
  for (int i = beg + t; i < end; i += 256) atomicAdd(&deg[tdst[i]], 1);
  __syncthreads();
  int v = deg[t];
  int lane = t & 63, wave = t >> 6;
  int inc = v;
  #pragma unroll
  for (int off = 1; off < 64; off <<= 1) {
    int u = __shfl_up(inc, off);
    if (lane >= off) inc += u;
  }
  if (lane == 63) woff[wave] = inc;
  __syncthreads();
  int wadd = 0;
  for (int w = 0; w < wave; ++w) wadd += woff[w];
  int excl = wadd + inc - v;
  int gnode = b * NPB + t;
  if (gnode < NN) rowstart[gnode] = beg + excl;
  cur[t] = beg + excl;
  __syncthreads();
  for (int i = beg + t; i < end; i += 256) {
    int p = atomicAdd(&cur[tdst[i]], 1);
    srcidx[p] = tsrc[i];
  }
}

// ---------------- K1 v5 (MFMA): z = x @ M + cvec via split-bf16 hi/lo.
__global__ __launch_bounds__(256) void k1_mfma(
    const float* __restrict__ x,
    const unsigned short* __restrict__ Bhi, const unsigned short* __restrict__ Blo,
    const float* __restrict__ cvec, float* __restrict__ z) {
  const int lane = threadIdx.x & 63;
  const int wid = (blockIdx.x * 256 + threadIdx.x) >> 6;
  const int row0 = wid * 16;
  if (row0 >= NN) return;
  const int g = lane >> 4;
  const int r = row0 + (lane & 15);
  const float* __restrict__ xr = x + (size_t)r * FI;
  f32x4 acc0 = {0.f, 0.f, 0.f, 0.f};
  f32x4 acc1 = {0.f, 0.f, 0.f, 0.f};
  for (int s = 0; s < KSTEPS; ++s) {
    const int k0 = s * 32 + g * 8;
    float xv[8];
    if (k0 + 8 <= FI) {
      float4 a = *(const float4*)&xr[k0];
      float4 b = *(const float4*)&xr[k0 + 4];
      xv[0] = a.x; xv[1] = a.y; xv[2] = a.z; xv[3] = a.w;
      xv[4] = b.x; xv[5] = b.y; xv[6] = b.z; xv[7] = b.w;
    } else {
      #pragma unroll
      for (int j = 0; j < 8; ++j) xv[j] = (k0 + j < FI) ? xr[k0 + j] : 0.f;
    }
    bf16x8 ahi, alo;
    #pragma unroll
    for (int j = 0; j < 8; ++j) {
      unsigned ub = __float_as_uint(xv[j]);
      unsigned short h = (unsigned short)(ub >> 16);
      float hv = __uint_as_float((unsigned)h << 16);
      float d = xv[j] - hv;
      ahi[j] = (short)h;
      alo[j] = (short)(__float_as_uint(d) >> 16);
    }
    const size_t fb = ((size_t)(s * 2) * 64 + lane) * 8;
    bf16x8 bh0 = *(const bf16x8*)&Bhi[fb];
    bf16x8 bl0 = *(const bf16x8*)&Blo[fb];
    bf16x8 bh1 = *(const bf16x8*)&Bhi[fb + 512];
    bf16x8 bl1 = *(const bf16x8*)&Blo[fb + 512];
    acc0 = __builtin_amdgcn_mfma_f32_16x16x32_bf16(ahi, bh0, acc0, 0, 0, 0);
    acc1 = __builtin_amdgcn_mfma_f32_16x16x32_bf16(ahi, bh1, acc1, 0, 0, 0);
    acc0 = __builtin_amdgcn_mfma_f32_16x16x32_bf16(alo, bh0, acc0, 0, 0, 0);
    acc1 = __builtin_amdgcn_mfma_f32_16x16x32_bf16(alo, bh1, acc1, 0, 0, 0);
    acc0 = __builtin_amdgcn_mfma_f32_16x16x32_bf16(ahi, bl0, acc0, 0, 0, 0);
    acc1 = __builtin_amdgcn_mfma_f32_16x16x32_bf16(ahi, bl1, acc1, 0, 0, 0);
  }
  const int c0 = lane & 15;
  const float cva = cvec[c0], cvb = cvec[16 + c0];
  #pragma unroll
  for (int j = 0; j < 4; ++j) {
    int rr = row0 + g * 4 + j;
    z[(size_t)rr * DD + c0] = acc0[j] + cva;
    z[(size_t)rr * DD + 16 + c0] = acc1[j] + cvb;
  }
}

// ---------------- K3 fused: per-thread node gather (self + in-edges of z) then MLP1 ; stats
__global__ __launch_bounds__(128) void k3_fused(
    const float* __restrict__ z, const int* __restrict__ rowstart,
    const int* __restrict__ srcidx,
    const float* __restrict__ w2, const float* __restrict__ b1, const float* __restrict__ b2,
    float* __restrict__ g1, float* __restrict__ stats) {
  __shared__ float w2s[DD * DD];
  __shared__ float ps[2][2 * DD];
  const int tid = threadIdx.x;
  const int n = blockIdx.x * 128 + tid;
  const bool valid = n < NN;
  for (int i = tid; i < DD * DD; i += 128) w2s[i] = w2[i];
  float acc[DD];
  int beg = 0, end = 0;
  if (valid) { beg = rowstart[n]; end = rowstart[n + 1]; }
  {
    const float* zr = valid ? &z[(size_t)n * DD] : z;
    #pragma unroll
    for (int j4 = 0; j4 < 8; ++j4) {
      float4 v = *(const float4*)&zr[j4 * 4];
      acc[j4 * 4 + 0] = v.x; acc[j4 * 4 + 1] = v.y;
      acc[j4 * 4 + 2] = v.z; acc[j4 * 4 + 3] = v.w;
    }
  }
  int i = beg;
  for (; i + 2 <= end; i += 2) {
    const float* r0 = &z[(size_t)srcidx[i] * DD];
    const float* r1 = &z[(size_t)srcidx[i + 1] * DD];
    #pragma unroll
    for (int j4 = 0; j4 < 8; ++j4) {
      float4 v0 = *(const float4*)&r0[j4 * 4];
      float4 v1 = *(const float4*)&r1[j4 * 4];
      acc[j4 * 4 + 0] += v0.x + v1.x;
      acc[j4 * 4 + 1] += v0.y + v1.y;
      acc[j4 * 4 + 2] += v0.z + v1.z;
      acc[j4 * 4 + 3] += v0.w + v1.w;
    }
  }
  if (i < end) {
    const float* r0 = &z[(size_t)srcidx[i] * DD];
    #pragma unroll
    for (int j4 = 0; j4 < 8; ++j4) {
      float4 v0 = *(const float4*)&r0[j4 * 4];
      acc[j4 * 4 + 0] += v0.x; acc[j4 * 4 + 1] += v0.y;
      acc[j4 * 4 + 2] += v0.z; acc[j4 * 4 + 3] += v0.w;
    }
  }
  __syncthreads();   // w2s ready
  float t[DD];
  #pragma unroll
  for (int k = 0; k < DD; ++k) t[k] = fmaxf(acc[k] + b1[k], 0.f);
  float g[DD];
  #pragma unroll
  for (int j = 0; j < DD; ++j) g[j] = b2[j];
  #pragma unroll
  for (int k = 0; k < DD; ++k) {
    float tv = t[k];
    #pragma unroll
    for (int j = 0; j < DD; ++j) g[j] = fmaf(tv, w2s[k * DD + j], g[j]);
  }
  int wave = tid >> 6, lane = tid & 63;
  #pragma unroll
  for (int j = 0; j < DD; ++j) {
    float v = valid ? g[j] : 0.f;
    float qq = v * v;
    #pragma unroll
    for (int off = 1; off < 64; off <<= 1) { v += __shfl_xor(v, off); qq += __shfl_xor(qq, off); }
    if (lane == 0) { ps[wave][j] = v; ps[wave][DD + j] = qq; }
  }
  __syncthreads();
  if (tid < 2 * DD) atomAdd(&stats[tid], ps[0][tid] + ps[1][tid]);
  if (valid) {
    float* gp = &g1[(size_t)n * DD];
    #pragma unroll
    for (int j4 = 0; j4 < 8; ++j4)
      *(float4*)&gp[j4 * 4] = make_float4(g[j4 * 4], g[j4 * 4 + 1], g[j4 * 4 + 2], g[j4 * 4 + 3]);
  }
}

// ---------------- K3b: BN1 params as (rs, sh): bn(y) = y*rs + sh
__global__ void k3b_bn(const float* __restrict__ stats, const float* __restrict__ gamma,
                       const float* __restrict__ beta, float* __restrict__ bnp) {
  int t = threadIdx.x;
  if (t < DD) {
    float mu = stats[t] * (1.f / NN);
    float var = stats[DD + t] * (1.f / NN) - mu * mu;
    float rs = rsqrtf(var + BN_EPS) * gamma[t];
    bnp[t] = rs;
    bnp[DD + t] = beta[t] - mu * rs;
  }
}

// ---------------- K6 fused: gather raw g1 (self + in-edges), BN-affine once
// (u = acc*rs + (1+deg)*sh), then MLP2 ; stats2
__global__ __launch_bounds__(128) void k6_fused(
    const float* __restrict__ g1, const int* __restrict__ rowstart,
    const int* __restrict__ srcidx, const float* __restrict__ bnp,
    const float* __restrict__ w1, const float* __restrict__ b1,
    const float* __restrict__ w2, const float* __restrict__ b2,
    float* __restrict__ g2, float* __restrict__ stats) {
  __shared__ float w1s[DD * DD];
  __shared__ float w2s[DD * DD];
  __shared__ float bns[2 * DD];
  __shared__ float ps[2][2 * DD];
  const int tid = threadIdx.x;
  const int n = blockIdx.x * 128 + tid;
  const bool valid = n < NN;
  for (int i = tid; i < DD * DD; i += 128) { w1s[i] = w1[i]; w2s[i] = w2[i]; }
  if (tid < 2 * DD) bns[tid] = bnp[tid];
  float acc[DD];
  int beg = 0, end = 0;
  if (valid) { beg = rowstart[n]; end = rowstart[n + 1]; }
  {
    const float* zr = valid ? &g1[(size_t)n * DD] : g1;
    #pragma unroll
    for (int j4 = 0; j4 < 8; ++j4) {
      float4 v = *(const float4*)&zr[j4 * 4];
      acc[j4 * 4 + 0] = v.x; acc[j4 * 4 + 1] = v.y;
      acc[j4 * 4 + 2] = v.z; acc[j4 * 4 + 3] = v.w;
    }
  }
  int i = beg;
  for (; i + 2 <= end; i += 2) {
    const float* r0 = &g1[(size_t)srcidx[i] * DD];
    const float* r1 = &g1[(size_t)srcidx[i + 1] * DD];
    #pragma unroll
    for (int j4 = 0; j4 < 8; ++j4) {
      float4 v0 = *(const float4*)&r0[j4 * 4];
      float4 v1 = *(const float4*)&r1[j4 * 4];
      acc[j4 * 4 + 0] += v0.x + v1.x;
      acc[j4 * 4 + 1] += v0.y + v1.y;
      acc[j4 * 4 + 2] += v0.z + v1.z;
      acc[j4 * 4 + 3] += v0.w + v1.w;
    }
  }
  if (i < end) {
    const float* r0 = &g1[(size_t)srcidx[i] * DD];
    #pragma unroll
    for (int j4 = 0; j4 < 8; ++j4) {
      float4 v0 = *(const float4*)&r0[j4 * 4];
      acc[j4 * 4 + 0] += v0.x; acc[j4 * 4 + 1] += v0.y;
      acc[j4 * 4 + 2] += v0.z; acc[j4 * 4 + 3] += v0.w;
    }
  }
  __syncthreads();   // w1s/w2s/bns ready
  const float degp1 = (float)(end - beg + 1);
  #pragma unroll
  for (int k = 0; k < DD; ++k) acc[k] = fmaf(acc[k], bns[k], degp1 * bns[DD + k]);
  float t1[DD];
  #pragma unroll
  for (int j = 0; j < DD; ++j) t1[j] = b1[j];
  #pragma unroll
  for (int k = 0; k < DD; ++k) {
    float uv = acc[k];
    #pragma unroll
    for (int j = 0; j < DD; ++j) t1[j] = fmaf(uv, w1s[k * DD + j], t1[j]);
  }
  #pragma unroll
  for (int j = 0; j < DD; ++j) t1[j] = fmaxf(t1[j], 0.f);
  float g[DD];
  #pragma unroll
  for (int j = 0; j < DD; ++j) g[j] = b2[j];
  #pragma unroll
  for (int k = 0; k < DD; ++k) {
    float tv = t1[k];
    #pragma unroll
    for (int j = 0; j < DD; ++j) g[j] = fmaf(tv, w2s[k * DD + j], g[j]);
  }
  int wave = tid >> 6, lane = tid & 63;
  #pragma unroll
  for (int j = 0; j < DD; ++j) {
    float v = valid ? g[j] : 0.f;
    float qq = v * v;
    #pragma unroll
    for (int off = 1; off < 64; off <<= 1) { v += __shfl_xor(v, off); qq += __shfl_xor(qq, off); }
    if (lane == 0) { ps[wave][j] = v; ps[wave][DD + j] = qq; }
  }
  __syncthreads();
  if (tid < 2 * DD) atomAdd(&stats[tid], ps[0][tid] + ps[1][tid]);
  if (valid) {
    float* gp = &g2[(size_t)n * DD];
    #pragma unroll
    for (int j4 = 0; j4 < 8; ++j4)
      *(float4*)&gp[j4 * 4] = make_float4(g[j4 * 4], g[j4 * 4 + 1], g[j4 * 4 + 2], g[j4 * 4 + 3]);
  }
}

// ---------------- K7: out = relu(bn2(g2)@fc1+b)@fc2+b
__global__ __launch_bounds__(256) void k7_head(
    const float* __restrict__ g2, const float* __restrict__ stats2,
    const float* __restrict__ bn2_g, const float* __restrict__ bn2_b,
    const float* __restrict__ fc1_w, const float* __restrict__ fc1_b,
    const float* __restrict__ fc2_w, const float* __restrict__ fc2_b,
    float* __restrict__ out) {
  __shared__ float buf[256 * 42];
  __shared__ float fc1s[DD * DD];
  __shared__ float fc2s[DD * CC];
  __shared__ float mu2[DD], rsg2[DD], bet2[DD];
  const int tid = threadIdx.x;
  const int n0 = blockIdx.x * 256;
  if (tid < DD) {
    float mu = stats2[tid] * (1.f / NN);
    float var = stats2[DD + tid] * (1.f / NN) - mu * mu;
    mu2[tid] = mu;
    rsg2[tid] = rsqrtf(var + BN_EPS) * bn2_g[tid];
    bet2[tid] = bn2_b[tid];
  }
  for (int i = tid; i < DD * DD; i += 256) fc1s[i] = fc1_w[i];
  for (int i = tid; i < DD * CC; i += 256) fc2s[i] = fc2_w[i];
  __syncthreads();
  #pragma unroll
  for (int i = 0; i < 32; ++i) {
    int l = tid + i * 256;
    int r = l >> 5, c = l & 31;
    float v = 0.f;
    if (n0 + r < NN) v = (g2[(size_t)(n0 + r) * DD + c] - mu2[c]) * rsg2[c] + bet2[c];
    buf[r * 33 + c] = v;
  }
  __syncthreads();
  float t[DD];
  #pragma unroll
  for (int j = 0; j < DD; ++j) t[j] = fc1_b[j];
  #pragma unroll
  for (int k = 0; k < DD; ++k) {
    float uv = buf[tid * 33 + k];
    #pragma unroll
    for (int j = 0; j < DD; ++j) t[j] = fmaf(uv, fc1s[k * DD + j], t[j]);
  }
  #pragma unroll
  for (int j = 0; j < DD; ++j) t[j] = fmaxf(t[j], 0.f);
  float o[CC];
  #pragma unroll
  for (int j = 0; j < CC; ++j) o[j] = fc2_b[j];
  #pragma unroll
  for (int k = 0; k < DD; ++k) {
    float tv = t[k];
    #pragma unroll
    for (int j = 0; j < CC; ++j) o[j] = fmaf(tv, fc2s[k * CC + j], o[j]);
  }
  __syncthreads();
  #pragma unroll
  for (int j = 0; j < CC; ++j) buf[tid * 42 + j] = o[j];
  __syncthreads();
  for (int i = 0; i < CC; ++i) {
    int l = tid + i * 256;
    int r = l / CC, c = l % CC;
    if (n0 + r < NN) out[(size_t)(n0 + r) * CC + c] = buf[r * 42 + c];
  }
}

extern "C" void kernel_launch(void* const* d_in, const int* in_sizes, int n_in,
                              void* d_out, int out_size, void* d_ws, size_t ws_size,
                              hipStream_t stream) {
  const float* x      = (const float*)d_in[0];
  const int*   ei     = (const int*)d_in[1];
  const float* lin1_w = (const float*)d_in[2];
  const float* lin1_b = (const float*)d_in[3];
  const float* nn1_w1 = (const float*)d_in[4];
  const float* nn1_b1 = (const float*)d_in[5];
  const float* nn1_w2 = (const float*)d_in[6];
  const float* nn1_b2 = (const float*)d_in[7];
  const float* bn1_g  = (const float*)d_in[8];
  const float* bn1_b  = (const float*)d_in[9];
  const float* nn2_w1 = (const float*)d_in[10];
  const float* nn2_b1 = (const float*)d_in[11];
  const float* nn2_w2 = (const float*)d_in[12];
  const float* nn2_b2 = (const float*)d_in[13];
  const float* bn2_g  = (const float*)d_in[14];
  const float* bn2_b  = (const float*)d_in[15];
  const float* fc1_w  = (const float*)d_in[16];
  const float* fc1_b  = (const float*)d_in[17];
  const float* fc2_w  = (const float*)d_in[18];
  const float* fc2_b  = (const float*)d_in[19];
  float* out = (float*)d_out;

  float* ws = (float*)d_ws;
  size_t nd = (size_t)NN * DD;
  float* A      = ws;            // z, then g2
  float* Cb     = ws + nd;       // g1
  float* cvec   = ws + 2 * nd;
  float* stats1 = cvec + 32;
  float* bnp1   = stats1 + 64;
  float* stats2 = bnp1 + 96;
  unsigned short* Bhi = (unsigned short*)(stats2 + 64);     // 19456 shorts
  unsigned short* Blo = Bhi + KSTEPS * 2 * 64 * 8;          // 19456 shorts
  int*   rowstart = (int*)(Blo + KSTEPS * 2 * 64 * 8);      // NN+1
  int*   srcidx   = rowstart + (NN + 1);                    // NE
  int*   tsrc     = srcidx + NE;                            // NE
  unsigned char* tdst = (unsigned char*)(tsrc + NE);        // NE bytes
  int*   bcount   = (int*)(tdst + NE);                      // NB
  int*   bcursor  = bcount + NB;                            // NB
  int*   bbase    = bcursor + NB;                           // NB+1

  // bucketed CSR build
  hipMemsetAsync(bcount, 0, NB * sizeof(int), stream);
  kb_hist<<<SCB, 256, 0, stream>>>(ei, bcount);
  kb_scan<<<1, 512, 0, stream>>>(bcount, bbase, bcursor, rowstart);
  kb_scatter<<<SCB, 256, 0, stream>>>(ei, bcursor, tsrc, tdst);
  kb_fine<<<NB, 256, 0, stream>>>(bbase, tsrc, tdst, rowstart, srcidx);

  k0_prep<<<(KSTEPS * 32 * 32 + 255) / 256, 256, 0, stream>>>(
      lin1_w, lin1_b, nn1_w1, Bhi, Blo, cvec, stats1, stats2);
  k1_mfma<<<(NN / 16 + 3) / 4, 256, 0, stream>>>(x, Bhi, Blo, cvec, A);
  k3_fused<<<(NN + 127) / 128, 128, 0, stream>>>(A, rowstart, srcidx, nn1_w2, nn1_b1, nn1_b2, Cb, stats1);
  k3b_bn<<<1, 64, 0, stream>>>(stats1, bn1_g, bn1_b, bnp1);
  k6_fused<<<(NN + 127) / 128, 128, 0, stream>>>(Cb, rowstart, srcidx, bnp1,
                                                 nn2_w1, nn2_b1, nn2_w2, nn2_b2, A, stats2);
  k7_head<<<(NN + 255) / 256, 256, 0, stream>>>(A, stats2, bn2_g, bn2_b, fc1_w, fc1_b, fc2_w, fc2_b, out);
}

// Round 10
// 344.247 us; speedup vs baseline: 2.0203x; 2.0203x over previous
//
#include <hip/hip_runtime.h>
#include <cstdint>

#define NN 100000
#define NE 1600000
#define FI 602
#define DD 32
#define CC 41
#define BN_EPS 1e-5f
#define KSTEPS 19                 // 19*32 = 608 >= 602 (k-padded with zeros)

// bucketed CSR build
#define NPB 256                   // nodes per bucket (dst >> 8)
#define NB 391                    // ceil(NN/NPB)
#define EPT 13                    // edges per thread in hist/scatter
#define SCB 481                   // ceil(NE / (256*EPT))

typedef __attribute__((ext_vector_type(8))) short bf16x8;
typedef __attribute__((ext_vector_type(4))) float f32x4;

__device__ __forceinline__ void atomAdd(float* p, float v) {
#ifdef __HIP_PLATFORM_AMD__
  unsafeAtomicAdd(p, v);
#else
  atomicAdd(p, v);
#endif
}

// round-to-nearest-even f32 -> bf16 bits
__device__ __forceinline__ unsigned short f2b(float f) {
  unsigned u = __float_as_uint(f);
  unsigned r = (u + 0x7fffu + ((u >> 16) & 1u)) >> 16;
  return (unsigned short)r;
}
__device__ __forceinline__ float blo(unsigned u) { return __uint_as_float(u << 16); }
__device__ __forceinline__ float bhi(unsigned u) { return __uint_as_float(u & 0xffff0000u); }

// ---------------- K0: M = lin1_w @ nn1_w1 as MFMA B-fragments (bf16 hi/lo) ; cvec ; zero stats
__global__ __launch_bounds__(256) void k0_prep(
    const float* __restrict__ lin1_w, const float* __restrict__ lin1_b,
    const float* __restrict__ nn1_w1,
    unsigned short* __restrict__ Bhi, unsigned short* __restrict__ Blo,
    float* __restrict__ cvec,
    float* __restrict__ stats1, float* __restrict__ stats2) {
  int o = blockIdx.x * 256 + threadIdx.x;   // over 608*32
  if (o < KSTEPS * 32 * 32) {
    int k = o >> 5, j = o & 31;
    float s = 0.f;
    if (k < FI) {
      #pragma unroll 4
      for (int c = 0; c < 2 * DD; ++c) s = fmaf(lin1_w[k * (2 * DD) + c], nn1_w1[c * DD + j], s);
    }
    int st = k >> 5, kk = k & 31, g = kk >> 3, jj = kk & 7;
    int h = j >> 4, lane = g * 16 + (j & 15);
    int idx = ((st * 2 + h) * 64 + lane) * 8 + jj;
    unsigned ub = __float_as_uint(s);
    unsigned short hi = (unsigned short)(ub >> 16);
    float hv = __uint_as_float((unsigned)hi << 16);
    float d = s - hv;
    Bhi[idx] = hi;
    Blo[idx] = (unsigned short)(__float_as_uint(d) >> 16);
  }
  if (blockIdx.x == 0) {
    int t = threadIdx.x;
    if (t < DD) {
      float s = 0.f;
      for (int c = 0; c < 2 * DD; ++c) s = fmaf(lin1_b[c], nn1_w1[c * DD + t], s);
      cvec[t] = s;
    }
    if (t >= 128 && t < 192) stats1[t - 128] = 0.f;
    if (t >= 192) stats2[t - 192] = 0.f;
  }
}

// ---------------- bucketed CSR build ----------------
__global__ __launch_bounds__(256) void kb_hist(const int* __restrict__ ei, int* __restrict__ bcount) {
  __shared__ int h[NB];
  const int t = threadIdx.x;
  for (int i = t; i < NB; i += 256) h[i] = 0;
  __syncthreads();
  const int base = blockIdx.x * (256 * EPT);
  #pragma unroll
  for (int i = 0; i < EPT; ++i) {
    int e = base + i * 256 + t;
    if (e < NE) atomicAdd(&h[ei[NE + e] >> 8], 1);
  }
  __syncthreads();
  for (int i = t; i < NB; i += 256) if (h[i]) atomicAdd(&bcount[i], h[i]);
}

__global__ __launch_bounds__(512) void kb_scan(const int* __restrict__ bcount,
                                               int* __restrict__ bbase,
                                               int* __restrict__ bcursor,
                                               int* __restrict__ rowstart) {
  __shared__ int ps[512];
  const int t = threadIdx.x;
  int v = (t < NB) ? bcount[t] : 0;
  ps[t] = v;
  __syncthreads();
  #pragma unroll
  for (int off = 1; off < 512; off <<= 1) {
    int u = (t >= off) ? ps[t - off] : 0;
    __syncthreads();
    ps[t] += u;
    __syncthreads();
  }
  int excl = ps[t] - v;
  if (t < NB) { bbase[t] = excl; bcursor[t] = excl; }
  if (t == 0) { bbase[NB] = NE; rowstart[NN] = NE; }
}

__global__ __launch_bounds__(256) void kb_scatter(const int* __restrict__ ei,
                                                  int* __restrict__ bcursor,
                                                  int* __restrict__ tsrc,
                                                  unsigned char* __restrict__ tdst) {
  __shared__ int cnt[NB];
  __shared__ int wbase[NB];
  const int t = threadIdx.x;
  for (int i = t; i < NB; i += 256) cnt[i] = 0;
  __syncthreads();
  const int base = blockIdx.x * (256 * EPT);
  int s[EPT], d[EPT];
  #pragma unroll
  for (int i = 0; i < EPT; ++i) {
    int e = base + i * 256 + t;
    if (e < NE) {
      s[i] = ei[e];
      d[i] = ei[NE + e];
      atomicAdd(&cnt[d[i] >> 8], 1);
    } else {
      s[i] = -1; d[i] = -1;
    }
  }
  __syncthreads();
  for (int i = t; i < NB; i += 256) wbase[i] = atomicAdd(&bcursor[i], cnt[i]);
  __syncthreads();
  #pragma unroll
  for (int i = 0; i < EPT; ++i) {
    if (d[i] >= 0) {
      int p = atomicAdd(&wbase[d[i] >> 8], 1);
      tsrc[p] = s[i];
      tdst[p] = (unsigned char)(d[i] & (NPB - 1));
    }
  }
}

__global__ __launch_bounds__(256) void kb_fine(const int* __restrict__ bbase,
                                               const int* __restrict__ tsrc,
                                               const unsigned char* __restrict__ tdst,
                                               int* __restrict__ rowstart,
                                               int* __restrict__ srcidx) {
  __shared__ int deg[NPB];
  __shared__ int cur[NPB];
  __shared__ int woff[4];
  const int b = blockIdx.x, t = threadIdx.x;
  const int beg = bbase[b], end = bbase[b + 1];
  deg[t] = 0;
  __syncthreads();
  for (int i = beg + t; i < end; i += 256) atomicAdd(&deg[tdst[i]], 1);
  __syncthreads();
  int v = deg[t];
  int lane = t & 63, wave = t >> 6;
  int inc = v;
  #pragma unroll
  for (int off = 1; off < 64; off <<= 1) {
    int u = __shfl_up(inc, off);
    if (lane >= off) inc += u;
  }
  if (lane == 63) woff[wave] = inc;
  __syncthreads();
  int wadd = 0;
  for (int w = 0; w < wave; ++w) wadd += woff[w];
  int excl = wadd + inc - v;
  int gnode = b * NPB + t;
  if (gnode < NN) rowstart[gnode] = beg + excl;
  cur[t] = beg + excl;
  __syncthreads();
  for (int i = beg + t; i < end; i += 256) {
    int p = atomicAdd(&cur[tdst[i]], 1);
    srcidx[p] = tsrc[i];
  }
}

// ---------------- K1 (MFMA): z = x @ M + cvec via split-bf16 hi/lo; also emit bf16 copy zb
__global__ __launch_bounds__(256) void k1_mfma(
    const float* __restrict__ x,
    const unsigned short* __restrict__ Bhi, const unsigned short* __restrict__ Blo,
    const float* __restrict__ cvec, float* __restrict__ z,
    unsigned short* __restrict__ zb) {
  const int lane = threadIdx.x & 63;
  const int wid = (blockIdx.x * 256 + threadIdx.x) >> 6;
  const int row0 = wid * 16;
  if (row0 >= NN) return;
  const int g = lane >> 4;
  const int r = row0 + (lane & 15);
  const float* __restrict__ xr = x + (size_t)r * FI;
  f32x4 acc0 = {0.f, 0.f, 0.f, 0.f};
  f32x4 acc1 = {0.f, 0.f, 0.f, 0.f};
  for (int s = 0; s < KSTEPS; ++s) {
    const int k0 = s * 32 + g * 8;
    float xv[8];
    if (k0 + 8 <= FI) {
      float4 a = *(const float4*)&xr[k0];
      float4 b = *(const float4*)&xr[k0 + 4];
      xv[0] = a.x; xv[1] = a.y; xv[2] = a.z; xv[3] = a.w;
      xv[4] = b.x; xv[5] = b.y; xv[6] = b.z; xv[7] = b.w;
    } else {
      #pragma unroll
      for (int j = 0; j < 8; ++j) xv[j] = (k0 + j < FI) ? xr[k0 + j] : 0.f;
    }
    bf16x8 ahi, alo;
    #pragma unroll
    for (int j = 0; j < 8; ++j) {
      unsigned ub = __float_as_uint(xv[j]);
      unsigned short h = (unsigned short)(ub >> 16);
      float hv = __uint_as_float((unsigned)h << 16);
      float d = xv[j] - hv;
      ahi[j] = (short)h;
      alo[j] = (short)(__float_as_uint(d) >> 16);
    }
    const size_t fb = ((size_t)(s * 2) * 64 + lane) * 8;
    bf16x8 bh0 = *(const bf16x8*)&Bhi[fb];
    bf16x8 bl0 = *(const bf16x8*)&Blo[fb];
    bf16x8 bh1 = *(const bf16x8*)&Bhi[fb + 512];
    bf16x8 bl1 = *(const bf16x8*)&Blo[fb + 512];
    acc0 = __builtin_amdgcn_mfma_f32_16x16x32_bf16(ahi, bh0, acc0, 0, 0, 0);
    acc1 = __builtin_amdgcn_mfma_f32_16x16x32_bf16(ahi, bh1, acc1, 0, 0, 0);
    acc0 = __builtin_amdgcn_mfma_f32_16x16x32_bf16(alo, bh0, acc0, 0, 0, 0);
    acc1 = __builtin_amdgcn_mfma_f32_16x16x32_bf16(alo, bh1, acc1, 0, 0, 0);
    acc0 = __builtin_amdgcn_mfma_f32_16x16x32_bf16(ahi, bl0, acc0, 0, 0, 0);
    acc1 = __builtin_amdgcn_mfma_f32_16x16x32_bf16(ahi, bl1, acc1, 0, 0, 0);
  }
  const int c0 = lane & 15;
  const float cva = cvec[c0], cvb = cvec[16 + c0];
  #pragma unroll
  for (int j = 0; j < 4; ++j) {
    int rr = row0 + g * 4 + j;
    float v0 = acc0[j] + cva;
    float v1 = acc1[j] + cvb;
    z[(size_t)rr * DD + c0] = v0;
    z[(size_t)rr * DD + 16 + c0] = v1;
    zb[(size_t)rr * DD + c0] = f2b(v0);
    zb[(size_t)rr * DD + 16 + c0] = f2b(v1);
  }
}

// ---------------- gather (bf16 operand): agg[n] = sum of src rows (raw, no BN)
// 4 lanes per node; each lane: 8 cols via one 16B bf16x8 load per edge, 4-edge ILP.
__global__ __launch_bounds__(256) void k_gather_b(const int* __restrict__ rowstart,
                                                  const int* __restrict__ srcidx,
                                                  const unsigned short* __restrict__ srcb,
                                                  float* __restrict__ agg) {
  int gid = blockIdx.x * 256 + threadIdx.x;
  int n = gid >> 2, q = gid & 3;
  if (n >= NN) return;
  int beg = rowstart[n], end = rowstart[n + 1];
  float a[8] = {};
  int i = beg;
  for (; i + 4 <= end; i += 4) {
    int s0 = srcidx[i], s1 = srcidx[i + 1], s2 = srcidx[i + 2], s3 = srcidx[i + 3];
    uint4 v0 = *(const uint4*)&srcb[(size_t)s0 * DD + q * 8];
    uint4 v1 = *(const uint4*)&srcb[(size_t)s1 * DD + q * 8];
    uint4 v2 = *(const uint4*)&srcb[(size_t)s2 * DD + q * 8];
    uint4 v3 = *(const uint4*)&srcb[(size_t)s3 * DD + q * 8];
    a[0] += blo(v0.x) + blo(v1.x) + blo(v2.x) + blo(v3.x);
    a[1] += bhi(v0.x) + bhi(v1.x) + bhi(v2.x) + bhi(v3.x);
    a[2] += blo(v0.y) + blo(v1.y) + blo(v2.y) + blo(v3.y);
    a[3] += bhi(v0.y) + bhi(v1.y) + bhi(v2.y) + bhi(v3.y);
    a[4] += blo(v0.z) + blo(v1.z) + blo(v2.z) + blo(v3.z);
    a[5] += bhi(v0.z) + bhi(v1.z) + bhi(v2.z) + bhi(v3.z);
    a[6] += blo(v0.w) + blo(v1.w) + blo(v2.w) + blo(v3.w);
    a[7] += bhi(v0.w) + bhi(v1.w) + bhi(v2.w) + bhi(v3.w);
  }
  for (; i < end; ++i) {
    uint4 v0 = *(const uint4*)&srcb[(size_t)srcidx[i] * DD + q * 8];
    a[0] += blo(v0.x); a[1] += bhi(v0.x);
    a[2] += blo(v0.y); a[3] += bhi(v0.y);
    a[4] += blo(v0.z); a[5] += bhi(v0.z);
    a[6] += blo(v0.w); a[7] += bhi(v0.w);
  }
  float* ap = &agg[(size_t)n * DD + q * 8];
  *(float4*)&ap[0] = make_float4(a[0], a[1], a[2], a[3]);
  *(float4*)&ap[4] = make_float4(a[4], a[5], a[6], a[7]);
}

// ---------------- K3: g1 = relu(z+agg+b1) @ w2 + b2 ; stats ; also emit bf16 copy g1b
__global__ __launch_bounds__(256) void k3_mlp1(
    const float* __restrict__ z, const float* __restrict__ agg,
    const float* __restrict__ w2, const float* __restrict__ b1, const float* __restrict__ b2,
    float* __restrict__ g1, unsigned short* __restrict__ g1b, float* __restrict__ stats) {
  __shared__ float us[256][DD + 1];
  __shared__ float w2s[DD][DD];
  __shared__ float ps[4][2 * DD];
  const int tid = threadIdx.x;
  const int n0 = blockIdx.x * 256;
  for (int i = tid; i < DD * DD; i += 256) w2s[i >> 5][i & 31] = w2[i];
  #pragma unroll
  for (int i = 0; i < 32; ++i) {
    int l = tid + i * 256;
    int r = l >> 5, c = l & 31;
    float v = 0.f;
    if (n0 + r < NN) {
      size_t gi = (size_t)(n0 + r) * DD + c;
      v = z[gi] + agg[gi];
    }
    us[r][c] = v;
  }
  __syncthreads();
  float t[DD];
  #pragma unroll
  for (int k = 0; k < DD; ++k) t[k] = fmaxf(us[tid][k] + b1[k], 0.f);
  float g[DD];
  #pragma unroll
  for (int j = 0; j < DD; ++j) g[j] = b2[j];
  #pragma unroll
  for (int k = 0; k < DD; ++k) {
    float tv = t[k];
    #pragma unroll
    for (int j = 0; j < DD; ++j) g[j] = fmaf(tv, w2s[k][j], g[j]);
  }
  bool valid = (n0 + tid) < NN;
  #pragma unroll
  for (int j = 0; j < DD; ++j) us[tid][j] = g[j];
  int wave = tid >> 6, lane = tid & 63;
  #pragma unroll
  for (int j = 0; j < DD; ++j) {
    float v = valid ? g[j] : 0.f;
    float qq = v * v;
    #pragma unroll
    for (int off = 1; off < 64; off <<= 1) { v += __shfl_xor(v, off); qq += __shfl_xor(qq, off); }
    if (lane == 0) { ps[wave][j] = v; ps[wave][DD + j] = qq; }
  }
  __syncthreads();
  if (tid < 2 * DD)
    atomAdd(&stats[tid], ps[0][tid] + ps[1][tid] + ps[2][tid] + ps[3][tid]);
  #pragma unroll
  for (int i = 0; i < 32; ++i) {
    int l = tid + i * 256;
    int r = l >> 5, c = l & 31;
    if (n0 + r < NN) {
      size_t gi = (size_t)(n0 + r) * DD + c;
      float v = us[r][c];
      g1[gi] = v;
      g1b[gi] = f2b(v);
    }
  }
}

// ---------------- K3b: BN1 params as (rs, sh): bn(y) = y*rs + sh
__global__ void k3b_bn(const float* __restrict__ stats, const float* __restrict__ gamma,
                       const float* __restrict__ beta, float* __restrict__ bnp) {
  int t = threadIdx.x;
  if (t < DD) {
    float mu = stats[t] * (1.f / NN);
    float var = stats[DD + t] * (1.f / NN) - mu * mu;
    float rs = rsqrtf(var + BN_EPS) * gamma[t];
    bnp[t] = rs;
    bnp[DD + t] = beta[t] - mu * rs;
  }
}

// ---------------- K6: u = (g1+aggRaw)*rs + (1+deg)*sh ; g2 = relu(u@w1+b1)@w2+b2 ; stats2
__global__ __launch_bounds__(256) void k6_mlp2(
    const float* __restrict__ g1, const float* __restrict__ agg,
    const int* __restrict__ rowstart, const float* __restrict__ bnp,
    const float* __restrict__ w1, const float* __restrict__ b1,
    const float* __restrict__ w2, const float* __restrict__ b2,
    float* __restrict__ g2, float* __restrict__ stats) {
  __shared__ float us[256][DD + 1];
  __shared__ float w1s[DD][DD];
  __shared__ float w2s[DD][DD];
  __shared__ float bns[2 * DD];
  __shared__ float ps[4][2 * DD];
  const int tid = threadIdx.x;
  const int n0 = blockIdx.x * 256;
  for (int i = tid; i < DD * DD; i += 256) { w1s[i >> 5][i & 31] = w1[i]; w2s[i >> 5][i & 31] = w2[i]; }
  if (tid < 2 * DD) bns[tid] = bnp[tid];
  const int n = n0 + tid;
  const bool valid = n < NN;
  float degp1 = 1.f;
  if (valid) degp1 = (float)(rowstart[n + 1] - rowstart[n] + 1);
  #pragma unroll
  for (int i = 0; i < 32; ++i) {
    int l = tid + i * 256;
    int r = l >> 5, c = l & 31;
    float v = 0.f;
    if (n0 + r < NN) {
      size_t gi = (size_t)(n0 + r) * DD + c;
      v = g1[gi] + agg[gi];
    }
    us[r][c] = v;
  }
  __syncthreads();
  float t1[DD];
  #pragma unroll
  for (int j = 0; j < DD; ++j) t1[j] = b1[j];
  #pragma unroll
  for (int k = 0; k < DD; ++k) {
    float uv = fmaf(us[tid][k], bns[k], degp1 * bns[DD + k]);
    #pragma unroll
    for (int j = 0; j < DD; ++j) t1[j] = fmaf(uv, w1s[k][j], t1[j]);
  }
  #pragma unroll
  for (int j = 0; j < DD; ++j) t1[j] = fmaxf(t1[j], 0.f);
  float g[DD];
  #pragma unroll
  for (int j = 0; j < DD; ++j) g[j] = b2[j];
  #pragma unroll
  for (int k = 0; k < DD; ++k) {
    float tv = t1[k];
    #pragma unroll
    for (int j = 0; j < DD; ++j) g[j] = fmaf(tv, w2s[k][j], g[j]);
  }
  #pragma unroll
  for (int j = 0; j < DD; ++j) us[tid][j] = g[j];
  int wave = tid >> 6, lane = tid & 63;
  #pragma unroll
  for (int j = 0; j < DD; ++j) {
    float v = valid ? g[j] : 0.f;
    float qq = v * v;
    #pragma unroll
    for (int off = 1; off < 64; off <<= 1) { v += __shfl_xor(v, off); qq += __shfl_xor(qq, off); }
    if (lane == 0) { ps[wave][j] = v; ps[wave][DD + j] = qq; }
  }
  __syncthreads();
  if (tid < 2 * DD)
    atomAdd(&stats[tid], ps[0][tid] + ps[1][tid] + ps[2][tid] + ps[3][tid]);
  #pragma unroll
  for (int i = 0; i < 32; ++i) {
    int l = tid + i * 256;
    int r = l >> 5, c = l & 31;
    if (n0 + r < NN) g2[(size_t)(n0 + r) * DD + c] = us[r][c];
  }
}

// ---------------- K7: out = relu(bn2(g2)@fc1+b)@fc2+b
__global__ __launch_bounds__(256) void k7_head(
    const float* __restrict__ g2, const float* __restrict__ stats2,
    const float* __restrict__ bn2_g, const float* __restrict__ bn2_b,
    const float* __restrict__ fc1_w, const float* __restrict__ fc1_b,
    const float* __restrict__ fc2_w, const float* __restrict__ fc2_b,
    float* __restrict__ out) {
  __shared__ float buf[256 * 42];
  __shared__ float fc1s[DD * DD];
  __shared__ float fc2s[DD * CC];
  __shared__ float mu2[DD], rsg2[DD], bet2[DD];
  const int tid = threadIdx.x;
  const int n0 = blockIdx.x * 256;
  if (tid < DD) {
    float mu = stats2[tid] * (1.f / NN);
    float var = stats2[DD + tid] * (1.f / NN) - mu * mu;
    mu2[tid] = mu;
    rsg2[tid] = rsqrtf(var + BN_EPS) * bn2_g[tid];
    bet2[tid] = bn2_b[tid];
  }
  for (int i = tid; i < DD * DD; i += 256) fc1s[i] = fc1_w[i];
  for (int i = tid; i < DD * CC; i += 256) fc2s[i] = fc2_w[i];
  __syncthreads();
  #pragma unroll
  for (int i = 0; i < 32; ++i) {
    int l = tid + i * 256;
    int r = l >> 5, c = l & 31;
    float v = 0.f;
    if (n0 + r < NN) v = (g2[(size_t)(n0 + r) * DD + c] - mu2[c]) * rsg2[c] + bet2[c];
    buf[r * 33 + c] = v;
  }
  __syncthreads();
  float t[DD];
  #pragma unroll
  for (int j = 0; j < DD; ++j) t[j] = fc1_b[j];
  #pragma unroll
  for (int k = 0; k < DD; ++k) {
    float uv = buf[tid * 33 + k];
    #pragma unroll
    for (int j = 0; j < DD; ++j) t[j] = fmaf(uv, fc1s[k * DD + j], t[j]);
  }
  #pragma unroll
  for (int j = 0; j < DD; ++j) t[j] = fmaxf(t[j], 0.f);
  float o[CC];
  #pragma unroll
  for (int j = 0; j < CC; ++j) o[j] = fc2_b[j];
  #pragma unroll
  for (int k = 0; k < DD; ++k) {
    float tv = t[k];
    #pragma unroll
    for (int j = 0; j < CC; ++j) o[j] = fmaf(tv, fc2s[k * CC + j], o[j]);
  }
  __syncthreads();
  #pragma unroll
  for (int j = 0; j < CC; ++j) buf[tid * 42 + j] = o[j];
  __syncthreads();
  for (int i = 0; i < CC; ++i) {
    int l = tid + i * 256;
    int r = l / CC, c = l % CC;
    if (n0 + r < NN) out[(size_t)(n0 + r) * CC + c] = buf[r * 42 + c];
  }
}

extern "C" void kernel_launch(void* const* d_in, const int* in_sizes, int n_in,
                              void* d_out, int out_size, void* d_ws, size_t ws_size,
                              hipStream_t stream) {
  const float* x      = (const float*)d_in[0];
  const int*   ei     = (const int*)d_in[1];
  const float* lin1_w = (const float*)d_in[2];
  const float* lin1_b = (const float*)d_in[3];
  const float* nn1_w1 = (const float*)d_in[4];
  const float* nn1_b1 = (const float*)d_in[5];
  const float* nn1_w2 = (const float*)d_in[6];
  const float* nn1_b2 = (const float*)d_in[7];
  const float* bn1_g  = (const float*)d_in[8];
  const float* bn1_b  = (const float*)d_in[9];
  const float* nn2_w1 = (const float*)d_in[10];
  const float* nn2_b1 = (const float*)d_in[11];
  const float* nn2_w2 = (const float*)d_in[12];
  const float* nn2_b2 = (const float*)d_in[13];
  const float* bn2_g  = (const float*)d_in[14];
  const float* bn2_b  = (const float*)d_in[15];
  const float* fc1_w  = (const float*)d_in[16];
  const float* fc1_b  = (const float*)d_in[17];
  const float* fc2_w  = (const float*)d_in[18];
  const float* fc2_b  = (const float*)d_in[19];
  float* out = (float*)d_out;

  float* ws = (float*)d_ws;
  size_t nd = (size_t)NN * DD;
  float* A      = ws;            // z, then g2
  float* B      = ws + nd;       // agg1, then agg2 (raw)
  float* Cb     = ws + 2 * nd;   // g1
  float* cvec   = ws + 3 * nd;
  float* stats1 = cvec + 32;
  float* bnp1   = stats1 + 64;
  float* stats2 = bnp1 + 96;
  unsigned short* Bhi = (unsigned short*)(stats2 + 64);     // 19456 shorts
  unsigned short* Blo = Bhi + KSTEPS * 2 * 64 * 8;          // 19456 shorts
  int*   rowstart = (int*)(Blo + KSTEPS * 2 * 64 * 8);      // NN+1
  int*   srcidx   = rowstart + (NN + 1);                    // NE
  int*   tsrc     = srcidx + NE;                            // NE ints; dead after kb_fine
  unsigned char* tdst = (unsigned char*)(tsrc + NE);        // NE bytes
  int*   bcount   = (int*)(tdst + NE);                      // NB
  int*   bcursor  = bcount + NB;                            // NB
  int*   bbase    = bcursor + NB;                           // NB+1
  // bf16 feature buffer (zb, then g1b) aliases the dead tsrc region: NN*32*2B = NE*4B exactly
  unsigned short* fb16 = (unsigned short*)tsrc;

  // bucketed CSR build
  hipMemsetAsync(bcount, 0, NB * sizeof(int), stream);
  kb_hist<<<SCB, 256, 0, stream>>>(ei, bcount);
  kb_scan<<<1, 512, 0, stream>>>(bcount, bbase, bcursor, rowstart);
  kb_scatter<<<SCB, 256, 0, stream>>>(ei, bcursor, tsrc, tdst);
  kb_fine<<<NB, 256, 0, stream>>>(bbase, tsrc, tdst, rowstart, srcidx);

  k0_prep<<<(KSTEPS * 32 * 32 + 255) / 256, 256, 0, stream>>>(
      lin1_w, lin1_b, nn1_w1, Bhi, Blo, cvec, stats1, stats2);
  k1_mfma<<<(NN / 16 + 3) / 4, 256, 0, stream>>>(x, Bhi, Blo, cvec, A, fb16);
  k_gather_b<<<(NN * 4 + 255) / 256, 256, 0, stream>>>(rowstart, srcidx, fb16, B);
  k3_mlp1<<<(NN + 255) / 256, 256, 0, stream>>>(A, B, nn1_w2, nn1_b1, nn1_b2, Cb, fb16, stats1);
  k3b_bn<<<1, 64, 0, stream>>>(stats1, bn1_g, bn1_b, bnp1);
  k_gather_b<<<(NN * 4 + 255) / 256, 256, 0, stream>>>(rowstart, srcidx, fb16, B);
  k6_mlp2<<<(NN + 255) / 256, 256, 0, stream>>>(Cb, B, rowstart, bnp1,
                                                nn2_w1, nn2_b1, nn2_w2, nn2_b2, A, stats2);
  k7_head<<<(NN + 255) / 256, 256, 0, stream>>>(A, stats2, bn2_g, bn2_b, fc1_w, fc1_b, fc2_w, fc2_b, out);
}

// Round 11
// 329.871 us; speedup vs baseline: 2.1083x; 1.0436x over previous
//
#include <hip/hip_runtime.h>
#include <cstdint>

#define NN 100000
#define NE 1600000
#define FI 602
#define DD 32
#define CC 41
#define BN_EPS 1e-5f
#define KSTEPS 19                 // 19*32 = 608 >= 602 (k-padded with zeros)

// bucketed CSR build
#define NPB 256                   // nodes per bucket (dst >> 8)
#define NB 391                    // ceil(NN/NPB)
#define EPT 13                    // edges per thread in hist/scatter
#define SCB 481                   // ceil(NE / (256*EPT))

typedef __attribute__((ext_vector_type(8))) short bf16x8;
typedef __attribute__((ext_vector_type(4))) float f32x4;

__device__ __forceinline__ void atomAdd(float* p, float v) {
#ifdef __HIP_PLATFORM_AMD__
  unsafeAtomicAdd(p, v);
#else
  atomicAdd(p, v);
#endif
}

// round-to-nearest-even f32 -> bf16 bits
__device__ __forceinline__ unsigned short f2b(float f) {
  unsigned u = __float_as_uint(f);
  unsigned r = (u + 0x7fffu + ((u >> 16) & 1u)) >> 16;
  return (unsigned short)r;
}
__device__ __forceinline__ float blo(unsigned u) { return __uint_as_float(u << 16); }
__device__ __forceinline__ float bhi(unsigned u) { return __uint_as_float(u & 0xffff0000u); }

// ---------------- K0: M = lin1_w @ nn1_w1 as MFMA B-fragments (bf16 hi/lo) ; cvec ; zero stats
__global__ __launch_bounds__(256) void k0_prep(
    const float* __restrict__ lin1_w, const float* __restrict__ lin1_b,
    const float* __restrict__ nn1_w1,
    unsigned short* __restrict__ Bhi, unsigned short* __restrict__ Blo,
    float* __restrict__ cvec,
    float* __restrict__ stats1, float* __restrict__ stats2) {
  int o = blockIdx.x * 256 + threadIdx.x;   // over 608*32
  if (o < KSTEPS * 32 * 32) {
    int k = o >> 5, j = o & 31;
    float s = 0.f;
    if (k < FI) {
      #pragma unroll 4
      for (int c = 0; c < 2 * DD; ++c) s = fmaf(lin1_w[k * (2 * DD) + c], nn1_w1[c * DD + j], s);
    }
    int st = k >> 5, kk = k & 31, g = kk >> 3, jj = kk & 7;
    int h = j >> 4, lane = g * 16 + (j & 15);
    int idx = ((st * 2 + h) * 64 + lane) * 8 + jj;
    unsigned ub = __float_as_uint(s);
    unsigned short hi = (unsigned short)(ub >> 16);
    float hv = __uint_as_float((unsigned)hi << 16);
    float d = s - hv;
    Bhi[idx] = hi;
    Blo[idx] = (unsigned short)(__float_as_uint(d) >> 16);
  }
  if (blockIdx.x == 0) {
    int t = threadIdx.x;
    if (t < DD) {
      float s = 0.f;
      for (int c = 0; c < 2 * DD; ++c) s = fmaf(lin1_b[c], nn1_w1[c * DD + t], s);
      cvec[t] = s;
    }
    if (t >= 128 && t < 192) stats1[t - 128] = 0.f;
    if (t >= 192) stats2[t - 192] = 0.f;
  }
}

// ---------------- bucketed CSR build ----------------
__global__ __launch_bounds__(256) void kb_hist(const int* __restrict__ ei, int* __restrict__ bcount) {
  __shared__ int h[NB];
  const int t = threadIdx.x;
  for (int i = t; i < NB; i += 256) h[i] = 0;
  __syncthreads();
  const int base = blockIdx.x * (256 * EPT);
  #pragma unroll
  for (int i = 0; i < EPT; ++i) {
    int e = base + i * 256 + t;
    if (e < NE) atomicAdd(&h[ei[NE + e] >> 8], 1);
  }
  __syncthreads();
  for (int i = t; i < NB; i += 256) if (h[i]) atomicAdd(&bcount[i], h[i]);
}

__global__ __launch_bounds__(512) void kb_scan(const int* __restrict__ bcount,
                                               int* __restrict__ bbase,
                                               int* __restrict__ bcursor,
                                               int* __restrict__ rowstart) {
  __shared__ int ps[512];
  const int t = threadIdx.x;
  int v = (t < NB) ? bcount[t] : 0;
  ps[t] = v;
  __syncthreads();
  #pragma unroll
  for (int off = 1; off < 512; off <<= 1) {
    int u = (t >= off) ? ps[t - off] : 0;
    __syncthreads();
    ps[t] += u;
    __syncthreads();
  }
  int excl = ps[t] - v;
  if (t < NB) { bbase[t] = excl; bcursor[t] = excl; }
  if (t == 0) { bbase[NB] = NE; rowstart[NN] = NE; }
}

__global__ __launch_bounds__(256) void kb_scatter(const int* __restrict__ ei,
                                                  int* __restrict__ bcursor,
                                                  int* __restrict__ tsrc,
                                                  unsigned char* __restrict__ tdst) {
  __shared__ int cnt[NB];
  __shared__ int wbase[NB];
  const int t = threadIdx.x;
  for (int i = t; i < NB; i += 256) cnt[i] = 0;
  __syncthreads();
  const int base = blockIdx.x * (256 * EPT);
  int s[EPT], d[EPT];
  #pragma unroll
  for (int i = 0; i < EPT; ++i) {
    int e = base + i * 256 + t;
    if (e < NE) {
      s[i] = ei[e];
      d[i] = ei[NE + e];
      atomicAdd(&cnt[d[i] >> 8], 1);
    } else {
      s[i] = -1; d[i] = -1;
    }
  }
  __syncthreads();
  for (int i = t; i < NB; i += 256) wbase[i] = atomicAdd(&bcursor[i], cnt[i]);
  __syncthreads();
  #pragma unroll
  for (int i = 0; i < EPT; ++i) {
    if (d[i] >= 0) {
      int p = atomicAdd(&wbase[d[i] >> 8], 1);
      tsrc[p] = s[i];
      tdst[p] = (unsigned char)(d[i] & (NPB - 1));
    }
  }
}

__global__ __launch_bounds__(256) void kb_fine(const int* __restrict__ bbase,
                                               const int* __restrict__ tsrc,
                                               const unsigned char* __restrict__ tdst,
                                               int* __restrict__ rowstart,
                                               int* __restrict__ srcidx) {
  __shared__ int deg[NPB];
  __shared__ int cur[NPB];
  __shared__ int woff[4];
  const int b = blockIdx.x, t = threadIdx.x;
  const int beg = bbase[b], end = bbase[b + 1];
  deg[t] = 0;
  __syncthreads();
  for (int i = beg + t; i < end; i += 256) atomicAdd(&deg[tdst[i]], 1);
  __syncthreads();
  int v = deg[t];
  int lane = t & 63, wave = t >> 6;
  int inc = v;
  #pragma unroll
  for (int off = 1; off < 64; off <<= 1) {
    int u = __shfl_up(inc, off);
    if (lane >= off) inc += u;
  }
  if (lane == 63) woff[wave] = inc;
  __syncthreads();
  int wadd = 0;
  for (int w = 0; w < wave; ++w) wadd += woff[w];
  int excl = wadd + inc - v;
  int gnode = b * NPB + t;
  if (gnode < NN) rowstart[gnode] = beg + excl;
  cur[t] = beg + excl;
  __syncthreads();
  for (int i = beg + t; i < end; i += 256) {
    int p = atomicAdd(&cur[tdst[i]], 1);
    srcidx[p] = tsrc[i];
  }
}

// ---------------- K1 v6 (MFMA, pipelined): zb = bf16(x @ M + cvec)
// 18 guard-free unrolled steps + explicit tail; depth-2 register prefetch of x.
__global__ __launch_bounds__(256) void k1_mfma(
    const float* __restrict__ x,
    const unsigned short* __restrict__ Bhi, const unsigned short* __restrict__ Blo,
    const float* __restrict__ cvec, unsigned short* __restrict__ zb) {
  const int lane = threadIdx.x & 63;
  const int wid = (blockIdx.x * 256 + threadIdx.x) >> 6;
  const int row0 = wid * 16;
  if (row0 >= NN) return;
  const int g = lane >> 4;
  const int r = row0 + (lane & 15);
  const float* __restrict__ xr = x + (size_t)r * FI + g * 8;
  f32x4 acc0 = {0.f, 0.f, 0.f, 0.f};
  f32x4 acc1 = {0.f, 0.f, 0.f, 0.f};

  // prefetch: a0/b0 = step s, a1/b1 = step s+1 (steps 0..17 unguarded: 17*32+24+8=576<=602)
  float4 a0 = *(const float4*)&xr[0];
  float4 b0 = *(const float4*)&xr[4];
  float4 a1 = *(const float4*)&xr[32];
  float4 b1 = *(const float4*)&xr[36];

  #pragma unroll
  for (int s = 0; s < KSTEPS - 1; ++s) {
    float4 ca = a0, cb = b0;
    a0 = a1; b0 = b1;
    if (s + 2 < KSTEPS - 1) {
      a1 = *(const float4*)&xr[(s + 2) * 32];
      b1 = *(const float4*)&xr[(s + 2) * 32 + 4];
    } else if (s + 2 == KSTEPS - 1) {
      // tail step 18: row offset 576+g*8; only g==3 (600..607) exceeds 602
      if (g == 3) {
        float2 t = *(const float2*)&xr[18 * 32];   // elements 600,601
        a1 = make_float4(t.x, t.y, 0.f, 0.f);
        b1 = make_float4(0.f, 0.f, 0.f, 0.f);
      } else {
        a1 = *(const float4*)&xr[18 * 32];
        b1 = *(const float4*)&xr[18 * 32 + 4];
      }
    }
    bf16x8 ahi, alo;
    {
      float cv0[8] = {ca.x, ca.y, ca.z, ca.w, cb.x, cb.y, cb.z, cb.w};
      #pragma unroll
      for (int j = 0; j < 8; ++j) {
        unsigned ub = __float_as_uint(cv0[j]);
        unsigned short h = (unsigned short)(ub >> 16);
        float hv = __uint_as_float(ub & 0xffff0000u);
        float d = cv0[j] - hv;
        ahi[j] = (short)h;
        alo[j] = (short)(__float_as_uint(d) >> 16);
      }
    }
    const size_t fb = ((size_t)(s * 2) * 64 + lane) * 8;
    bf16x8 bh0 = *(const bf16x8*)&Bhi[fb];
    bf16x8 bl0 = *(const bf16x8*)&Blo[fb];
    bf16x8 bh1 = *(const bf16x8*)&Bhi[fb + 512];
    bf16x8 bl1 = *(const bf16x8*)&Blo[fb + 512];
    acc0 = __builtin_amdgcn_mfma_f32_16x16x32_bf16(ahi, bh0, acc0, 0, 0, 0);
    acc1 = __builtin_amdgcn_mfma_f32_16x16x32_bf16(ahi, bh1, acc1, 0, 0, 0);
    acc0 = __builtin_amdgcn_mfma_f32_16x16x32_bf16(alo, bh0, acc0, 0, 0, 0);
    acc1 = __builtin_amdgcn_mfma_f32_16x16x32_bf16(alo, bh1, acc1, 0, 0, 0);
    acc0 = __builtin_amdgcn_mfma_f32_16x16x32_bf16(ahi, bl0, acc0, 0, 0, 0);
    acc1 = __builtin_amdgcn_mfma_f32_16x16x32_bf16(ahi, bl1, acc1, 0, 0, 0);
  }
  // tail step 18 (data in a0/b0)
  {
    bf16x8 ahi, alo;
    float cv0[8] = {a0.x, a0.y, a0.z, a0.w, b0.x, b0.y, b0.z, b0.w};
    #pragma unroll
    for (int j = 0; j < 8; ++j) {
      unsigned ub = __float_as_uint(cv0[j]);
      unsigned short h = (unsigned short)(ub >> 16);
      float hv = __uint_as_float(ub & 0xffff0000u);
      float d = cv0[j] - hv;
      ahi[j] = (short)h;
      alo[j] = (short)(__float_as_uint(d) >> 16);
    }
    const size_t fb = ((size_t)((KSTEPS - 1) * 2) * 64 + lane) * 8;
    bf16x8 bh0 = *(const bf16x8*)&Bhi[fb];
    bf16x8 bl0 = *(const bf16x8*)&Blo[fb];
    bf16x8 bh1 = *(const bf16x8*)&Bhi[fb + 512];
    bf16x8 bl1 = *(const bf16x8*)&Blo[fb + 512];
    acc0 = __builtin_amdgcn_mfma_f32_16x16x32_bf16(ahi, bh0, acc0, 0, 0, 0);
    acc1 = __builtin_amdgcn_mfma_f32_16x16x32_bf16(ahi, bh1, acc1, 0, 0, 0);
    acc0 = __builtin_amdgcn_mfma_f32_16x16x32_bf16(alo, bh0, acc0, 0, 0, 0);
    acc1 = __builtin_amdgcn_mfma_f32_16x16x32_bf16(alo, bh1, acc1, 0, 0, 0);
    acc0 = __builtin_amdgcn_mfma_f32_16x16x32_bf16(ahi, bl0, acc0, 0, 0, 0);
    acc1 = __builtin_amdgcn_mfma_f32_16x16x32_bf16(ahi, bl1, acc1, 0, 0, 0);
  }
  // C/D layout: col = lane&15, row = (lane>>4)*4 + reg. Store bf16 only.
  const int c0 = lane & 15;
  const float cva = cvec[c0], cvb = cvec[16 + c0];
  #pragma unroll
  for (int j = 0; j < 4; ++j) {
    int rr = row0 + g * 4 + j;
    zb[(size_t)rr * DD + c0] = f2b(acc0[j] + cva);
    zb[(size_t)rr * DD + 16 + c0] = f2b(acc1[j] + cvb);
  }
}

// ---------------- gather (bf16 operand): agg[n] = sum of src rows (raw, no BN)
__global__ __launch_bounds__(256) void k_gather_b(const int* __restrict__ rowstart,
                                                  const int* __restrict__ srcidx,
                                                  const unsigned short* __restrict__ srcb,
                                                  float* __restrict__ agg) {
  int gid = blockIdx.x * 256 + threadIdx.x;
  int n = gid >> 2, q = gid & 3;
  if (n >= NN) return;
  int beg = rowstart[n], end = rowstart[n + 1];
  float a[8] = {};
  int i = beg;
  for (; i + 4 <= end; i += 4) {
    int s0 = srcidx[i], s1 = srcidx[i + 1], s2 = srcidx[i + 2], s3 = srcidx[i + 3];
    uint4 v0 = *(const uint4*)&srcb[(size_t)s0 * DD + q * 8];
    uint4 v1 = *(const uint4*)&srcb[(size_t)s1 * DD + q * 8];
    uint4 v2 = *(const uint4*)&srcb[(size_t)s2 * DD + q * 8];
    uint4 v3 = *(const uint4*)&srcb[(size_t)s3 * DD + q * 8];
    a[0] += blo(v0.x) + blo(v1.x) + blo(v2.x) + blo(v3.x);
    a[1] += bhi(v0.x) + bhi(v1.x) + bhi(v2.x) + bhi(v3.x);
    a[2] += blo(v0.y) + blo(v1.y) + blo(v2.y) + blo(v3.y);
    a[3] += bhi(v0.y) + bhi(v1.y) + bhi(v2.y) + bhi(v3.y);
    a[4] += blo(v0.z) + blo(v1.z) + blo(v2.z) + blo(v3.z);
    a[5] += bhi(v0.z) + bhi(v1.z) + bhi(v2.z) + bhi(v3.z);
    a[6] += blo(v0.w) + blo(v1.w) + blo(v2.w) + blo(v3.w);
    a[7] += bhi(v0.w) + bhi(v1.w) + bhi(v2.w) + bhi(v3.w);
  }
  for (; i < end; ++i) {
    uint4 v0 = *(const uint4*)&srcb[(size_t)srcidx[i] * DD + q * 8];
    a[0] += blo(v0.x); a[1] += bhi(v0.x);
    a[2] += blo(v0.y); a[3] += bhi(v0.y);
    a[4] += blo(v0.z); a[5] += bhi(v0.z);
    a[6] += blo(v0.w); a[7] += bhi(v0.w);
  }
  float* ap = &agg[(size_t)n * DD + q * 8];
  *(float4*)&ap[0] = make_float4(a[0], a[1], a[2], a[3]);
  *(float4*)&ap[4] = make_float4(a[4], a[5], a[6], a[7]);
}

// ---------------- K3: g1b = bf16(relu(zb+agg+b1) @ w2 + b2) ; stats
// In-place safe: each block reads its own rows of zb before overwriting them as g1b.
__global__ __launch_bounds__(256) void k3_mlp1(
    const unsigned short* __restrict__ zb, const float* __restrict__ agg,
    const float* __restrict__ w2, const float* __restrict__ b1, const float* __restrict__ b2,
    unsigned short* __restrict__ g1b, float* __restrict__ stats) {
  __shared__ float us[256][DD + 1];
  __shared__ float w2s[DD][DD];
  __shared__ float ps[4][2 * DD];
  const int tid = threadIdx.x;
  const int n0 = blockIdx.x * 256;
  for (int i = tid; i < DD * DD; i += 256) w2s[i >> 5][i & 31] = w2[i];
  #pragma unroll
  for (int i = 0; i < 16; ++i) {
    int l = tid + i * 256;
    int r = l >> 4, c2 = l & 15;
    float lo = 0.f, hi = 0.f;
    if (n0 + r < NN) {
      size_t gi = (size_t)(n0 + r) * DD + c2 * 2;
      unsigned u = *(const unsigned*)&zb[gi];
      float2 ag = *(const float2*)&agg[gi];
      lo = blo(u) + ag.x;
      hi = bhi(u) + ag.y;
    }
    us[r][c2 * 2] = lo;
    us[r][c2 * 2 + 1] = hi;
  }
  __syncthreads();
  float t[DD];
  #pragma unroll
  for (int k = 0; k < DD; ++k) t[k] = fmaxf(us[tid][k] + b1[k], 0.f);
  float g[DD];
  #pragma unroll
  for (int j = 0; j < DD; ++j) g[j] = b2[j];
  #pragma unroll
  for (int k = 0; k < DD; ++k) {
    float tv = t[k];
    #pragma unroll
    for (int j = 0; j < DD; ++j) g[j] = fmaf(tv, w2s[k][j], g[j]);
  }
  bool valid = (n0 + tid) < NN;
  #pragma unroll
  for (int j = 0; j < DD; ++j) us[tid][j] = g[j];
  int wave = tid >> 6, lane = tid & 63;
  #pragma unroll
  for (int j = 0; j < DD; ++j) {
    float v = valid ? g[j] : 0.f;
    float qq = v * v;
    #pragma unroll
    for (int off = 1; off < 64; off <<= 1) { v += __shfl_xor(v, off); qq += __shfl_xor(qq, off); }
    if (lane == 0) { ps[wave][j] = v; ps[wave][DD + j] = qq; }
  }
  __syncthreads();
  if (tid < 2 * DD)
    atomAdd(&stats[tid], ps[0][tid] + ps[1][tid] + ps[2][tid] + ps[3][tid]);
  #pragma unroll
  for (int i = 0; i < 16; ++i) {
    int l = tid + i * 256;
    int r = l >> 4, c2 = l & 15;
    if (n0 + r < NN) {
      unsigned u = ((unsigned)f2b(us[r][c2 * 2 + 1]) << 16) | (unsigned)f2b(us[r][c2 * 2]);
      *(unsigned*)&g1b[(size_t)(n0 + r) * DD + c2 * 2] = u;
    }
  }
}

// ---------------- K3b: BN1 params as (rs, sh): bn(y) = y*rs + sh
__global__ void k3b_bn(const float* __restrict__ stats, const float* __restrict__ gamma,
                       const float* __restrict__ beta, float* __restrict__ bnp) {
  int t = threadIdx.x;
  if (t < DD) {
    float mu = stats[t] * (1.f / NN);
    float var = stats[DD + t] * (1.f / NN) - mu * mu;
    float rs = rsqrtf(var + BN_EPS) * gamma[t];
    bnp[t] = rs;
    bnp[DD + t] = beta[t] - mu * rs;
  }
}

// ---------------- K6: u = (g1b+aggRaw)*rs + (1+deg)*sh ; g2 = relu(u@w1+b1)@w2+b2 ; stats2
__global__ __launch_bounds__(256) void k6_mlp2(
    const unsigned short* __restrict__ g1b, const float* __restrict__ agg,
    const int* __restrict__ rowstart, const float* __restrict__ bnp,
    const float* __restrict__ w1, const float* __restrict__ b1,
    const float* __restrict__ w2, const float* __restrict__ b2,
    float* __restrict__ g2, float* __restrict__ stats) {
  __shared__ float us[256][DD + 1];
  __shared__ float w1s[DD][DD];
  __shared__ float w2s[DD][DD];
  __shared__ float bns[2 * DD];
  __shared__ float ps[4][2 * DD];
  const int tid = threadIdx.x;
  const int n0 = blockIdx.x * 256;
  for (int i = tid; i < DD * DD; i += 256) { w1s[i >> 5][i & 31] = w1[i]; w2s[i >> 5][i & 31] = w2[i]; }
  if (tid < 2 * DD) bns[tid] = bnp[tid];
  const int n = n0 + tid;
  const bool valid = n < NN;
  float degp1 = 1.f;
  if (valid) degp1 = (float)(rowstart[n + 1] - rowstart[n] + 1);
  #pragma unroll
  for (int i = 0; i < 16; ++i) {
    int l = tid + i * 256;
    int r = l >> 4, c2 = l & 15;
    float lo = 0.f, hi = 0.f;
    if (n0 + r < NN) {
      size_t gi = (size_t)(n0 + r) * DD + c2 * 2;
      unsigned u = *(const unsigned*)&g1b[gi];
      float2 ag = *(const float2*)&agg[gi];
      lo = blo(u) + ag.x;
      hi = bhi(u) + ag.y;
    }
    us[r][c2 * 2] = lo;
    us[r][c2 * 2 + 1] = hi;
  }
  __syncthreads();
  float t1[DD];
  #pragma unroll
  for (int j = 0; j < DD; ++j) t1[j] = b1[j];
  #pragma unroll
  for (int k = 0; k < DD; ++k) {
    float uv = fmaf(us[tid][k], bns[k], degp1 * bns[DD + k]);
    #pragma unroll
    for (int j = 0; j < DD; ++j) t1[j] = fmaf(uv, w1s[k][j], t1[j]);
  }
  #pragma unroll
  for (int j = 0; j < DD; ++j) t1[j] = fmaxf(t1[j], 0.f);
  float g[DD];
  #pragma unroll
  for (int j = 0; j < DD; ++j) g[j] = b2[j];
  #pragma unroll
  for (int k = 0; k < DD; ++k) {
    float tv = t1[k];
    #pragma unroll
    for (int j = 0; j < DD; ++j) g[j] = fmaf(tv, w2s[k][j], g[j]);
  }
  #pragma unroll
  for (int j = 0; j < DD; ++j) us[tid][j] = g[j];
  int wave = tid >> 6, lane = tid & 63;
  #pragma unroll
  for (int j = 0; j < DD; ++j) {
    float v = valid ? g[j] : 0.f;
    float qq = v * v;
    #pragma unroll
    for (int off = 1; off < 64; off <<= 1) { v += __shfl_xor(v, off); qq += __shfl_xor(qq, off); }
    if (lane == 0) { ps[wave][j] = v; ps[wave][DD + j] = qq; }
  }
  __syncthreads();
  if (tid < 2 * DD)
    atomAdd(&stats[tid], ps[0][tid] + ps[1][tid] + ps[2][tid] + ps[3][tid]);
  #pragma unroll
  for (int i = 0; i < 32; ++i) {
    int l = tid + i * 256;
    int r = l >> 5, c = l & 31;
    if (n0 + r < NN) g2[(size_t)(n0 + r) * DD + c] = us[r][c];
  }
}

// ---------------- K7: out = relu(bn2(g2)@fc1+b)@fc2+b
__global__ __launch_bounds__(256) void k7_head(
    const float* __restrict__ g2, const float* __restrict__ stats2,
    const float* __restrict__ bn2_g, const float* __restrict__ bn2_b,
    const float* __restrict__ fc1_w, const float* __restrict__ fc1_b,
    const float* __restrict__ fc2_w, const float* __restrict__ fc2_b,
    float* __restrict__ out) {
  __shared__ float buf[256 * 42];
  __shared__ float fc1s[DD * DD];
  __shared__ float fc2s[DD * CC];
  __shared__ float mu2[DD], rsg2[DD], bet2[DD];
  const int tid = threadIdx.x;
  const int n0 = blockIdx.x * 256;
  if (tid < DD) {
    float mu = stats2[tid] * (1.f / NN);
    float var = stats2[DD + tid] * (1.f / NN) - mu * mu;
    mu2[tid] = mu;
    rsg2[tid] = rsqrtf(var + BN_EPS) * bn2_g[tid];
    bet2[tid] = bn2_b[tid];
  }
  for (int i = tid; i < DD * DD; i += 256) fc1s[i] = fc1_w[i];
  for (int i = tid; i < DD * CC; i += 256) fc2s[i] = fc2_w[i];
  __syncthreads();
  #pragma unroll
  for (int i = 0; i < 32; ++i) {
    int l = tid + i * 256;
    int r = l >> 5, c = l & 31;
    float v = 0.f;
    if (n0 + r < NN) v = (g2[(size_t)(n0 + r) * DD + c] - mu2[c]) * rsg2[c] + bet2[c];
    buf[r * 33 + c] = v;
  }
  __syncthreads();
  float t[DD];
  #pragma unroll
  for (int j = 0; j < DD; ++j) t[j] = fc1_b[j];
  #pragma unroll
  for (int k = 0; k < DD; ++k) {
    float uv = buf[tid * 33 + k];
    #pragma unroll
    for (int j = 0; j < DD; ++j) t[j] = fmaf(uv, fc1s[k * DD + j], t[j]);
  }
  #pragma unroll
  for (int j = 0; j < DD; ++j) t[j] = fmaxf(t[j], 0.f);
  float o[CC];
  #pragma unroll
  for (int j = 0; j < CC; ++j) o[j] = fc2_b[j];
  #pragma unroll
  for (int k = 0; k < DD; ++k) {
    float tv = t[k];
    #pragma unroll
    for (int j = 0; j < CC; ++j) o[j] = fmaf(tv, fc2s[k * CC + j], o[j]);
  }
  __syncthreads();
  #pragma unroll
  for (int j = 0; j < CC; ++j) buf[tid * 42 + j] = o[j];
  __syncthreads();
  for (int i = 0; i < CC; ++i) {
    int l = tid + i * 256;
    int r = l / CC, c = l % CC;
    if (n0 + r < NN) out[(size_t)(n0 + r) * CC + c] = buf[r * 42 + c];
  }
}

extern "C" void kernel_launch(void* const* d_in, const int* in_sizes, int n_in,
                              void* d_out, int out_size, void* d_ws, size_t ws_size,
                              hipStream_t stream) {
  const float* x      = (const float*)d_in[0];
  const int*   ei     = (const int*)d_in[1];
  const float* lin1_w = (const float*)d_in[2];
  const float* lin1_b = (const float*)d_in[3];
  const float* nn1_w1 = (const float*)d_in[4];
  const float* nn1_b1 = (const float*)d_in[5];
  const float* nn1_w2 = (const float*)d_in[6];
  const float* nn1_b2 = (const float*)d_in[7];
  const float* bn1_g  = (const float*)d_in[8];
  const float* bn1_b  = (const float*)d_in[9];
  const float* nn2_w1 = (const float*)d_in[10];
  const float* nn2_b1 = (const float*)d_in[11];
  const float* nn2_w2 = (const float*)d_in[12];
  const float* nn2_b2 = (const float*)d_in[13];
  const float* bn2_g  = (const float*)d_in[14];
  const float* bn2_b  = (const float*)d_in[15];
  const float* fc1_w  = (const float*)d_in[16];
  const float* fc1_b  = (const float*)d_in[17];
  const float* fc2_w  = (const float*)d_in[18];
  const float* fc2_b  = (const float*)d_in[19];
  float* out = (float*)d_out;

  float* ws = (float*)d_ws;
  size_t nd = (size_t)NN * DD;
  float* A      = ws;            // g2 (f32)
  float* B      = ws + nd;       // agg1, then agg2 (raw f32)
  float* cvec   = ws + 2 * nd;
  float* stats1 = cvec + 32;
  float* bnp1   = stats1 + 64;
  float* stats2 = bnp1 + 96;
  unsigned short* Bhi = (unsigned short*)(stats2 + 64);     // 19456 shorts
  unsigned short* Blo = Bhi + KSTEPS * 2 * 64 * 8;          // 19456 shorts
  int*   rowstart = (int*)(Blo + KSTEPS * 2 * 64 * 8);      // NN+1
  int*   srcidx   = rowstart + (NN + 1);                    // NE
  int*   tsrc     = srcidx + NE;                            // NE ints; dead after kb_fine
  unsigned char* tdst = (unsigned char*)(tsrc + NE);        // NE bytes
  int*   bcount   = (int*)(tdst + NE);                      // NB
  int*   bcursor  = bcount + NB;                            // NB
  int*   bbase    = bcursor + NB;                           // NB+1
  // bf16 feature buffer (zb, then g1b in place) aliases dead tsrc: NN*32*2B = NE*4B
  unsigned short* fb16 = (unsigned short*)tsrc;

  // bucketed CSR build
  hipMemsetAsync(bcount, 0, NB * sizeof(int), stream);
  kb_hist<<<SCB, 256, 0, stream>>>(ei, bcount);
  kb_scan<<<1, 512, 0, stream>>>(bcount, bbase, bcursor, rowstart);
  kb_scatter<<<SCB, 256, 0, stream>>>(ei, bcursor, tsrc, tdst);
  kb_fine<<<NB, 256, 0, stream>>>(bbase, tsrc, tdst, rowstart, srcidx);

  k0_prep<<<(KSTEPS * 32 * 32 + 255) / 256, 256, 0, stream>>>(
      lin1_w, lin1_b, nn1_w1, Bhi, Blo, cvec, stats1, stats2);
  k1_mfma<<<(NN / 16 + 3) / 4, 256, 0, stream>>>(x, Bhi, Blo, cvec, fb16);
  k_gather_b<<<(NN * 4 + 255) / 256, 256, 0, stream>>>(rowstart, srcidx, fb16, B);
  k3_mlp1<<<(NN + 255) / 256, 256, 0, stream>>>(fb16, B, nn1_w2, nn1_b1, nn1_b2, fb16, stats1);
  k3b_bn<<<1, 64, 0, stream>>>(stats1, bn1_g, bn1_b, bnp1);
  k_gather_b<<<(NN * 4 + 255) / 256, 256, 0, stream>>>(rowstart, srcidx, fb16, B);
  k6_mlp2<<<(NN + 255) / 256, 256, 0, stream>>>(fb16, B, rowstart, bnp1,
                                                nn2_w1, nn2_b1, nn2_w2, nn2_b2, A, stats2);
  k7_head<<<(NN + 255) / 256, 256, 0, stream>>>(A, stats2, bn2_g, bn2_b, fc1_w, fc1_b, fc2_w, fc2_b, out);
}

// Round 12
// 277.896 us; speedup vs baseline: 2.5026x; 1.1870x over previous
//
#include <hip/hip_runtime.h>
#include <cstdint>

#define NN 100000
#define NE 1600000
#define FI 602
#define DD 32
#define CC 41
#define BN_EPS 1e-5f
#define KSTEPS 19                 // 19*32 = 608 >= 602 (k-padded with zeros)

// single-pass bucketed CSR build
#define NPB 256                   // nodes per bucket (dst >> 8)
#define NB 391                    // ceil(NN/NPB)
#define BST 4608                  // fixed bucket stride (mean 4096, sigma 64 -> 8-sigma margin)
#define EPT 13                    // edges per thread in scatter
#define SCB 481                   // ceil(NE / (256*EPT))

typedef __attribute__((ext_vector_type(8))) short bf16x8;
typedef __attribute__((ext_vector_type(4))) float f32x4;

__device__ __forceinline__ void atomAdd(float* p, float v) {
#ifdef __HIP_PLATFORM_AMD__
  unsafeAtomicAdd(p, v);
#else
  atomicAdd(p, v);
#endif
}

// round-to-nearest-even f32 -> bf16 bits
__device__ __forceinline__ unsigned short f2b(float f) {
  unsigned u = __float_as_uint(f);
  unsigned r = (u + 0x7fffu + ((u >> 16) & 1u)) >> 16;
  return (unsigned short)r;
}
__device__ __forceinline__ float blo(unsigned u) { return __uint_as_float(u << 16); }
__device__ __forceinline__ float bhi(unsigned u) { return __uint_as_float(u & 0xffff0000u); }

// ---------------- K0: M = lin1_w @ nn1_w1 as MFMA B-fragments (single RNE bf16) ; cvec ; zero stats
__global__ __launch_bounds__(256) void k0_prep(
    const float* __restrict__ lin1_w, const float* __restrict__ lin1_b,
    const float* __restrict__ nn1_w1,
    unsigned short* __restrict__ Bh,
    float* __restrict__ cvec,
    float* __restrict__ stats1, float* __restrict__ stats2) {
  int o = blockIdx.x * 256 + threadIdx.x;   // over 608*32
  if (o < KSTEPS * 32 * 32) {
    int k = o >> 5, j = o & 31;
    float s = 0.f;
    if (k < FI) {
      #pragma unroll 4
      for (int c = 0; c < 2 * DD; ++c) s = fmaf(lin1_w[k * (2 * DD) + c], nn1_w1[c * DD + j], s);
    }
    int st = k >> 5, kk = k & 31, g = kk >> 3, jj = kk & 7;
    int h = j >> 4, lane = g * 16 + (j & 15);
    int idx = ((st * 2 + h) * 64 + lane) * 8 + jj;
    Bh[idx] = f2b(s);
  }
  if (blockIdx.x == 0) {
    int t = threadIdx.x;
    if (t < DD) {
      float s = 0.f;
      for (int c = 0; c < 2 * DD; ++c) s = fmaf(lin1_b[c], nn1_w1[c * DD + t], s);
      cvec[t] = s;
    }
    if (t >= 128 && t < 192) stats1[t - 128] = 0.f;
    if (t >= 192) stats2[t - 192] = 0.f;
  }
}

// ---------------- single-pass scatter into fixed-stride buckets ----------------
__global__ __launch_bounds__(256) void kb_scatter(const int* __restrict__ ei,
                                                  int* __restrict__ bcursor,
                                                  int* __restrict__ tsrc,
                                                  unsigned char* __restrict__ tdst) {
  __shared__ int cnt[NB];
  __shared__ int wbase[NB];
  const int t = threadIdx.x;
  for (int i = t; i < NB; i += 256) cnt[i] = 0;
  __syncthreads();
  const int base = blockIdx.x * (256 * EPT);
  int s[EPT], d[EPT];
  #pragma unroll
  for (int i = 0; i < EPT; ++i) {
    int e = base + i * 256 + t;
    if (e < NE) {
      s[i] = ei[e];
      d[i] = ei[NE + e];
      atomicAdd(&cnt[d[i] >> 8], 1);
    } else {
      s[i] = -1; d[i] = -1;
    }
  }
  __syncthreads();
  for (int i = t; i < NB; i += 256) wbase[i] = atomicAdd(&bcursor[i], cnt[i]);
  __syncthreads();
  #pragma unroll
  for (int i = 0; i < EPT; ++i) {
    if (d[i] >= 0) {
      int bk = d[i] >> 8;
      int p = atomicAdd(&wbase[bk], 1);
      int gp = bk * BST + p;
      tsrc[gp] = s[i];
      tdst[gp] = (unsigned char)(d[i] & (NPB - 1));
    }
  }
}

// ---------------- per-bucket fine sort: rs/re + compact srcidx (bucket-strided CSR)
__global__ __launch_bounds__(256) void kb_fine(const int* __restrict__ bcursor,
                                               const int* __restrict__ tsrc,
                                               const unsigned char* __restrict__ tdst,
                                               int* __restrict__ rs, int* __restrict__ re,
                                               int* __restrict__ srcidx) {
  __shared__ int deg[NPB];
  __shared__ int cur[NPB];
  __shared__ int woff[4];
  const int b = blockIdx.x, t = threadIdx.x;
  const int beg = b * BST;
  const int end = beg + bcursor[b];
  deg[t] = 0;
  __syncthreads();
  for (int i = beg + t; i < end; i += 256) atomicAdd(&deg[tdst[i]], 1);
  __syncthreads();
  int v = deg[t];
  int lane = t & 63, wave = t >> 6;
  int inc = v;
  #pragma unroll
  for (int off = 1; off < 64; off <<= 1) {
    int u = __shfl_up(inc, off);
    if (lane >= off) inc += u;
  }
  if (lane == 63) woff[wave] = inc;
  __syncthreads();
  int wadd = 0;
  for (int w = 0; w < wave; ++w) wadd += woff[w];
  int excl = wadd + inc - v;
  int gnode = b * NPB + t;
  if (gnode < NN) {
    rs[gnode] = beg + excl;
    re[gnode] = beg + excl + v;
  }
  cur[t] = beg + excl;
  __syncthreads();
  for (int i = beg + t; i < end; i += 256) {
    int p = atomicAdd(&cur[tdst[i]], 1);
    srcidx[p] = tsrc[i];
  }
}

// ---------------- K1 v7 (MFMA): zb = bf16(x @ M + cvec)
// x split hi/lo (exact), M single RNE bf16 -> 4 MFMA / 2 frag loads per step.
// depth-2 x register prefetch + depth-1 frag register prefetch; fully unrolled.
__global__ __launch_bounds__(256) void k1_mfma(
    const float* __restrict__ x,
    const unsigned short* __restrict__ Bh,
    const float* __restrict__ cvec, unsigned short* __restrict__ zb) {
  const int lane = threadIdx.x & 63;
  const int wid = (blockIdx.x * 256 + threadIdx.x) >> 6;
  const int row0 = wid * 16;
  if (row0 >= NN) return;
  const int g = lane >> 4;
  const int r = row0 + (lane & 15);
  const float* __restrict__ xr = x + (size_t)r * FI + g * 8;
  f32x4 acc0 = {0.f, 0.f, 0.f, 0.f};
  f32x4 acc1 = {0.f, 0.f, 0.f, 0.f};

  // x prefetch: a0/b0 = step s, a1/b1 = step s+1
  float4 a0 = *(const float4*)&xr[0];
  float4 b0 = *(const float4*)&xr[4];
  float4 a1 = *(const float4*)&xr[32];
  float4 b1 = *(const float4*)&xr[36];
  // frag prefetch: current step
  bf16x8 f0c = *(const bf16x8*)&Bh[(size_t)lane * 8];
  bf16x8 f1c = *(const bf16x8*)&Bh[(size_t)lane * 8 + 512];

  #pragma unroll
  for (int s = 0; s < KSTEPS; ++s) {
    float4 ca = a0, cb = b0;
    a0 = a1; b0 = b1;
    if (s + 2 < KSTEPS - 1) {
      a1 = *(const float4*)&xr[(s + 2) * 32];
      b1 = *(const float4*)&xr[(s + 2) * 32 + 4];
    } else if (s + 2 == KSTEPS - 1) {
      // tail step 18: cols 576+g*8 .. ; only g==3 (600..607) exceeds 602
      if (g == 3) {
        float2 tt = *(const float2*)&xr[18 * 32];   // cols 600,601
        a1 = make_float4(tt.x, tt.y, 0.f, 0.f);
        b1 = make_float4(0.f, 0.f, 0.f, 0.f);
      } else {
        a1 = *(const float4*)&xr[18 * 32];
        b1 = *(const float4*)&xr[18 * 32 + 4];
      }
    }
    bf16x8 f0n, f1n;
    if (s + 1 < KSTEPS) {
      const size_t fb = ((size_t)((s + 1) * 2) * 64 + lane) * 8;
      f0n = *(const bf16x8*)&Bh[fb];
      f1n = *(const bf16x8*)&Bh[fb + 512];
    }
    bf16x8 ahi, alo;
    {
      float cv0[8] = {ca.x, ca.y, ca.z, ca.w, cb.x, cb.y, cb.z, cb.w};
      #pragma unroll
      for (int j = 0; j < 8; ++j) {
        unsigned ub = __float_as_uint(cv0[j]);
        unsigned short h = (unsigned short)(ub >> 16);
        float hv = __uint_as_float(ub & 0xffff0000u);
        float d = cv0[j] - hv;
        ahi[j] = (short)h;
        alo[j] = (short)(__float_as_uint(d) >> 16);
      }
    }
    acc0 = __builtin_amdgcn_mfma_f32_16x16x32_bf16(ahi, f0c, acc0, 0, 0, 0);
    acc1 = __builtin_amdgcn_mfma_f32_16x16x32_bf16(ahi, f1c, acc1, 0, 0, 0);
    acc0 = __builtin_amdgcn_mfma_f32_16x16x32_bf16(alo, f0c, acc0, 0, 0, 0);
    acc1 = __builtin_amdgcn_mfma_f32_16x16x32_bf16(alo, f1c, acc1, 0, 0, 0);
    if (s + 1 < KSTEPS) { f0c = f0n; f1c = f1n; }
  }
  // C/D layout: col = lane&15, row = (lane>>4)*4 + reg. Store bf16 only.
  const int c0 = lane & 15;
  const float cva = cvec[c0], cvb = cvec[16 + c0];
  #pragma unroll
  for (int j = 0; j < 4; ++j) {
    int rr = row0 + g * 4 + j;
    zb[(size_t)rr * DD + c0] = f2b(acc0[j] + cva);
    zb[(size_t)rr * DD + 16 + c0] = f2b(acc1[j] + cvb);
  }
}

// ---------------- gather (bf16 operand): agg[n] = sum of src rows (raw, no BN)
__global__ __launch_bounds__(256) void k_gather_b(const int* __restrict__ rs,
                                                  const int* __restrict__ re,
                                                  const int* __restrict__ srcidx,
                                                  const unsigned short* __restrict__ srcb,
                                                  float* __restrict__ agg) {
  int gid = blockIdx.x * 256 + threadIdx.x;
  int n = gid >> 2, q = gid & 3;
  if (n >= NN) return;
  int beg = rs[n], end = re[n];
  float a[8] = {};
  int i = beg;
  for (; i + 4 <= end; i += 4) {
    int s0 = srcidx[i], s1 = srcidx[i + 1], s2 = srcidx[i + 2], s3 = srcidx[i + 3];
    uint4 v0 = *(const uint4*)&srcb[(size_t)s0 * DD + q * 8];
    uint4 v1 = *(const uint4*)&srcb[(size_t)s1 * DD + q * 8];
    uint4 v2 = *(const uint4*)&srcb[(size_t)s2 * DD + q * 8];
    uint4 v3 = *(const uint4*)&srcb[(size_t)s3 * DD + q * 8];
    a[0] += blo(v0.x) + blo(v1.x) + blo(v2.x) + blo(v3.x);
    a[1] += bhi(v0.x) + bhi(v1.x) + bhi(v2.x) + bhi(v3.x);
    a[2] += blo(v0.y) + blo(v1.y) + blo(v2.y) + blo(v3.y);
    a[3] += bhi(v0.y) + bhi(v1.y) + bhi(v2.y) + bhi(v3.y);
    a[4] += blo(v0.z) + blo(v1.z) + blo(v2.z) + blo(v3.z);
    a[5] += bhi(v0.z) + bhi(v1.z) + bhi(v2.z) + bhi(v3.z);
    a[6] += blo(v0.w) + blo(v1.w) + blo(v2.w) + blo(v3.w);
    a[7] += bhi(v0.w) + bhi(v1.w) + bhi(v2.w) + bhi(v3.w);
  }
  for (; i < end; ++i) {
    uint4 v0 = *(const uint4*)&srcb[(size_t)srcidx[i] * DD + q * 8];
    a[0] += blo(v0.x); a[1] += bhi(v0.x);
    a[2] += blo(v0.y); a[3] += bhi(v0.y);
    a[4] += blo(v0.z); a[5] += bhi(v0.z);
    a[6] += blo(v0.w); a[7] += bhi(v0.w);
  }
  float* ap = &agg[(size_t)n * DD + q * 8];
  *(float4*)&ap[0] = make_float4(a[0], a[1], a[2], a[3]);
  *(float4*)&ap[4] = make_float4(a[4], a[5], a[6], a[7]);
}

// ---------------- K3: g1b = bf16(relu(zb+agg+b1) @ w2 + b2) ; stats (in-place zb->g1b)
__global__ __launch_bounds__(256) void k3_mlp1(
    const unsigned short* __restrict__ zb, const float* __restrict__ agg,
    const float* __restrict__ w2, const float* __restrict__ b1, const float* __restrict__ b2,
    unsigned short* __restrict__ g1b, float* __restrict__ stats) {
  __shared__ float us[256][DD + 1];
  __shared__ float w2s[DD][DD];
  __shared__ float ps[4][2 * DD];
  const int tid = threadIdx.x;
  const int n0 = blockIdx.x * 256;
  for (int i = tid; i < DD * DD; i += 256) w2s[i >> 5][i & 31] = w2[i];
  #pragma unroll
  for (int i = 0; i < 16; ++i) {
    int l = tid + i * 256;
    int r = l >> 4, c2 = l & 15;
    float lo = 0.f, hi = 0.f;
    if (n0 + r < NN) {
      size_t gi = (size_t)(n0 + r) * DD + c2 * 2;
      unsigned u = *(const unsigned*)&zb[gi];
      float2 ag = *(const float2*)&agg[gi];
      lo = blo(u) + ag.x;
      hi = bhi(u) + ag.y;
    }
    us[r][c2 * 2] = lo;
    us[r][c2 * 2 + 1] = hi;
  }
  __syncthreads();
  float t[DD];
  #pragma unroll
  for (int k = 0; k < DD; ++k) t[k] = fmaxf(us[tid][k] + b1[k], 0.f);
  float g[DD];
  #pragma unroll
  for (int j = 0; j < DD; ++j) g[j] = b2[j];
  #pragma unroll
  for (int k = 0; k < DD; ++k) {
    float tv = t[k];
    #pragma unroll
    for (int j = 0; j < DD; ++j) g[j] = fmaf(tv, w2s[k][j], g[j]);
  }
  bool valid = (n0 + tid) < NN;
  #pragma unroll
  for (int j = 0; j < DD; ++j) us[tid][j] = g[j];
  int wave = tid >> 6, lane = tid & 63;
  #pragma unroll
  for (int j = 0; j < DD; ++j) {
    float v = valid ? g[j] : 0.f;
    float qq = v * v;
    #pragma unroll
    for (int off = 1; off < 64; off <<= 1) { v += __shfl_xor(v, off); qq += __shfl_xor(qq, off); }
    if (lane == 0) { ps[wave][j] = v; ps[wave][DD + j] = qq; }
  }
  __syncthreads();
  if (tid < 2 * DD)
    atomAdd(&stats[tid], ps[0][tid] + ps[1][tid] + ps[2][tid] + ps[3][tid]);
  #pragma unroll
  for (int i = 0; i < 16; ++i) {
    int l = tid + i * 256;
    int r = l >> 4, c2 = l & 15;
    if (n0 + r < NN) {
      unsigned u = ((unsigned)f2b(us[r][c2 * 2 + 1]) << 16) | (unsigned)f2b(us[r][c2 * 2]);
      *(unsigned*)&g1b[(size_t)(n0 + r) * DD + c2 * 2] = u;
    }
  }
}

// ---------------- K3b: BN1 params as (rs, sh): bn(y) = y*rs + sh
__global__ void k3b_bn(const float* __restrict__ stats, const float* __restrict__ gamma,
                       const float* __restrict__ beta, float* __restrict__ bnp) {
  int t = threadIdx.x;
  if (t < DD) {
    float mu = stats[t] * (1.f / NN);
    float var = stats[DD + t] * (1.f / NN) - mu * mu;
    float rsv = rsqrtf(var + BN_EPS) * gamma[t];
    bnp[t] = rsv;
    bnp[DD + t] = beta[t] - mu * rsv;
  }
}

// ---------------- K6: u = (g1b+aggRaw)*rs + (1+deg)*sh ; g2 = relu(u@w1+b1)@w2+b2 ; stats2
__global__ __launch_bounds__(256) void k6_mlp2(
    const unsigned short* __restrict__ g1b, const float* __restrict__ agg,
    const int* __restrict__ rsA, const int* __restrict__ reA, const float* __restrict__ bnp,
    const float* __restrict__ w1, const float* __restrict__ b1,
    const float* __restrict__ w2, const float* __restrict__ b2,
    float* __restrict__ g2, float* __restrict__ stats) {
  __shared__ float us[256][DD + 1];
  __shared__ float w1s[DD][DD];
  __shared__ float w2s[DD][DD];
  __shared__ float bns[2 * DD];
  __shared__ float ps[4][2 * DD];
  const int tid = threadIdx.x;
  const int n0 = blockIdx.x * 256;
  for (int i = tid; i < DD * DD; i += 256) { w1s[i >> 5][i & 31] = w1[i]; w2s[i >> 5][i & 31] = w2[i]; }
  if (tid < 2 * DD) bns[tid] = bnp[tid];
  const int n = n0 + tid;
  const bool valid = n < NN;
  float degp1 = 1.f;
  if (valid) degp1 = (float)(reA[n] - rsA[n] + 1);
  #pragma unroll
  for (int i = 0; i < 16; ++i) {
    int l = tid + i * 256;
    int r = l >> 4, c2 = l & 15;
    float lo = 0.f, hi = 0.f;
    if (n0 + r < NN) {
      size_t gi = (size_t)(n0 + r) * DD + c2 * 2;
      unsigned u = *(const unsigned*)&g1b[gi];
      float2 ag = *(const float2*)&agg[gi];
      lo = blo(u) + ag.x;
      hi = bhi(u) + ag.y;
    }
    us[r][c2 * 2] = lo;
    us[r][c2 * 2 + 1] = hi;
  }
  __syncthreads();
  float t1[DD];
  #pragma unroll
  for (int j = 0; j < DD; ++j) t1[j] = b1[j];
  #pragma unroll
  for (int k = 0; k < DD; ++k) {
    float uv = fmaf(us[tid][k], bns[k], degp1 * bns[DD + k]);
    #pragma unroll
    for (int j = 0; j < DD; ++j) t1[j] = fmaf(uv, w1s[k][j], t1[j]);
  }
  #pragma unroll
  for (int j = 0; j < DD; ++j) t1[j] = fmaxf(t1[j], 0.f);
  float g[DD];
  #pragma unroll
  for (int j = 0; j < DD; ++j) g[j] = b2[j];
  #pragma unroll
  for (int k = 0; k < DD; ++k) {
    float tv = t1[k];
    #pragma unroll
    for (int j = 0; j < DD; ++j) g[j] = fmaf(tv, w2s[k][j], g[j]);
  }
  #pragma unroll
  for (int j = 0; j < DD; ++j) us[tid][j] = g[j];
  int wave = tid >> 6, lane = tid & 63;
  #pragma unroll
  for (int j = 0; j < DD; ++j) {
    float v = valid ? g[j] : 0.f;
    float qq = v * v;
    #pragma unroll
    for (int off = 1; off < 64; off <<= 1) { v += __shfl_xor(v, off); qq += __shfl_xor(qq, off); }
    if (lane == 0) { ps[wave][j] = v; ps[wave][DD + j] = qq; }
  }
  __syncthreads();
  if (tid < 2 * DD)
    atomAdd(&stats[tid], ps[0][tid] + ps[1][tid] + ps[2][tid] + ps[3][tid]);
  #pragma unroll
  for (int i = 0; i < 32; ++i) {
    int l = tid + i * 256;
    int r = l >> 5, c = l & 31;
    if (n0 + r < NN) g2[(size_t)(n0 + r) * DD + c] = us[r][c];
  }
}

// ---------------- K7: out = relu(bn2(g2)@fc1+b)@fc2+b
__global__ __launch_bounds__(256) void k7_head(
    const float* __restrict__ g2, const float* __restrict__ stats2,
    const float* __restrict__ bn2_g, const float* __restrict__ bn2_b,
    const float* __restrict__ fc1_w, const float* __restrict__ fc1_b,
    const float* __restrict__ fc2_w, const float* __restrict__ fc2_b,
    float* __restrict__ out) {
  __shared__ float buf[256 * 42];
  __shared__ float fc1s[DD * DD];
  __shared__ float fc2s[DD * CC];
  __shared__ float mu2[DD], rsg2[DD], bet2[DD];
  const int tid = threadIdx.x;
  const int n0 = blockIdx.x * 256;
  if (tid < DD) {
    float mu = stats2[tid] * (1.f / NN);
    float var = stats2[DD + tid] * (1.f / NN) - mu * mu;
    mu2[tid] = mu;
    rsg2[tid] = rsqrtf(var + BN_EPS) * bn2_g[tid];
    bet2[tid] = bn2_b[tid];
  }
  for (int i = tid; i < DD * DD; i += 256) fc1s[i] = fc1_w[i];
  for (int i = tid; i < DD * CC; i += 256) fc2s[i] = fc2_w[i];
  __syncthreads();
  #pragma unroll
  for (int i = 0; i < 32; ++i) {
    int l = tid + i * 256;
    int r = l >> 5, c = l & 31;
    float v = 0.f;
    if (n0 + r < NN) v = (g2[(size_t)(n0 + r) * DD + c] - mu2[c]) * rsg2[c] + bet2[c];
    buf[r * 33 + c] = v;
  }
  __syncthreads();
  float t[DD];
  #pragma unroll
  for (int j = 0; j < DD; ++j) t[j] = fc1_b[j];
  #pragma unroll
  for (int k = 0; k < DD; ++k) {
    float uv = buf[tid * 33 + k];
    #pragma unroll
    for (int j = 0; j < DD; ++j) t[j] = fmaf(uv, fc1s[k * DD + j], t[j]);
  }
  #pragma unroll
  for (int j = 0; j < DD; ++j) t[j] = fmaxf(t[j], 0.f);
  float o[CC];
  #pragma unroll
  for (int j = 0; j < CC; ++j) o[j] = fc2_b[j];
  #pragma unroll
  for (int k = 0; k < DD; ++k) {
    float tv = t[k];
    #pragma unroll
    for (int j = 0; j < CC; ++j) o[j] = fmaf(tv, fc2s[k * CC + j], o[j]);
  }
  __syncthreads();
  #pragma unroll
  for (int j = 0; j < CC; ++j) buf[tid * 42 + j] = o[j];
  __syncthreads();
  for (int i = 0; i < CC; ++i) {
    int l = tid + i * 256;
    int r = l / CC, c = l % CC;
    if (n0 + r < NN) out[(size_t)(n0 + r) * CC + c] = buf[r * 42 + c];
  }
}

extern "C" void kernel_launch(void* const* d_in, const int* in_sizes, int n_in,
                              void* d_out, int out_size, void* d_ws, size_t ws_size,
                              hipStream_t stream) {
  const float* x      = (const float*)d_in[0];
  const int*   ei     = (const int*)d_in[1];
  const float* lin1_w = (const float*)d_in[2];
  const float* lin1_b = (const float*)d_in[3];
  const float* nn1_w1 = (const float*)d_in[4];
  const float* nn1_b1 = (const float*)d_in[5];
  const float* nn1_w2 = (const float*)d_in[6];
  const float* nn1_b2 = (const float*)d_in[7];
  const float* bn1_g  = (const float*)d_in[8];
  const float* bn1_b  = (const float*)d_in[9];
  const float* nn2_w1 = (const float*)d_in[10];
  const float* nn2_b1 = (const float*)d_in[11];
  const float* nn2_w2 = (const float*)d_in[12];
  const float* nn2_b2 = (const float*)d_in[13];
  const float* bn2_g  = (const float*)d_in[14];
  const float* bn2_b  = (const float*)d_in[15];
  const float* fc1_w  = (const float*)d_in[16];
  const float* fc1_b  = (const float*)d_in[17];
  const float* fc2_w  = (const float*)d_in[18];
  const float* fc2_b  = (const float*)d_in[19];
  float* out = (float*)d_out;

  float* ws = (float*)d_ws;
  size_t nd = (size_t)NN * DD;
  float* A      = ws;            // g2 (f32)
  float* B      = ws + nd;       // agg (raw f32)
  float* cvec   = ws + 2 * nd;
  float* stats1 = cvec + 32;
  float* bnp1   = stats1 + 64;
  float* stats2 = bnp1 + 96;
  unsigned short* Bh = (unsigned short*)(stats2 + 64);      // 19456 shorts (38 KB)
  int*   rsA      = (int*)(Bh + KSTEPS * 2 * 64 * 8);       // NN
  int*   reA      = rsA + NN;                               // NN
  int*   srcidx   = reA + NN;                               // NB*BST
  int*   tsrc     = srcidx + (size_t)NB * BST;              // NB*BST ints; dead after kb_fine
  unsigned char* tdst = (unsigned char*)(tsrc + (size_t)NB * BST);  // NB*BST bytes
  int*   bcursor  = (int*)(tdst + (size_t)NB * BST);        // NB
  // bf16 feature buffer (zb, then g1b in place) aliases dead tsrc (7.2MB >= 6.4MB)
  unsigned short* fb16 = (unsigned short*)tsrc;

  // single-pass bucketed CSR build
  hipMemsetAsync(bcursor, 0, NB * sizeof(int), stream);
  kb_scatter<<<SCB, 256, 0, stream>>>(ei, bcursor, tsrc, tdst);
  kb_fine<<<NB, 256, 0, stream>>>(bcursor, tsrc, tdst, rsA, reA, srcidx);

  k0_prep<<<(KSTEPS * 32 * 32 + 255) / 256, 256, 0, stream>>>(
      lin1_w, lin1_b, nn1_w1, Bh, cvec, stats1, stats2);
  k1_mfma<<<(NN / 16 + 3) / 4, 256, 0, stream>>>(x, Bh, cvec, fb16);
  k_gather_b<<<(NN * 4 + 255) / 256, 256, 0, stream>>>(rsA, reA, srcidx, fb16, B);
  k3_mlp1<<<(NN + 255) / 256, 256, 0, stream>>>(fb16, B, nn1_w2, nn1_b1, nn1_b2, fb16, stats1);
  k3b_bn<<<1, 64, 0, stream>>>(stats1, bn1_g, bn1_b, bnp1);
  k_gather_b<<<(NN * 4 + 255) / 256, 256, 0, stream>>>(rsA, reA, srcidx, fb16, B);
  k6_mlp2<<<(NN + 255) / 256, 256, 0, stream>>>(fb16, B, rsA, reA, bnp1,
                                                nn2_w1, nn2_b1, nn2_w2, nn2_b2, A, stats2);
  k7_head<<<(NN + 255) / 256, 256, 0, stream>>>(A, stats2, bn2_g, bn2_b, fc1_w, fc1_b, fc2_w, fc2_b, out);
}